// Round 9
// baseline (12974.319 us; speedup 1.0000x reference)
//
#include <hip/hip_runtime.h>
#include <math.h>

// NOTE: binary spike outputs require BIT-EXACT reproduction of the validated
// reduction orders (rounds 2/5/6/8). All GEMM kernels below produce the same
// per-output ascending-k fmaf chain; tile shape / BK / buffering only change
// staging, so they can be mixed freely. Layer-6 pruning (round 8, validated)
// computes a subset of identical values.

// ---------------- device helpers ----------------
__device__ __forceinline__ float gelu_f(float x) {
    const float c = 0.7978845608028654f; // sqrt(2/pi)
    float x3 = x * x * x;
    float inner = c * (x + 0.044715f * x3);
    return 0.5f * x * (1.0f + tanhf(inner));
}

__device__ __forceinline__ int suffix_off(int g) {
    int b = g / 90, r = g - b * 90;
    return b * 4095 + 90 * r - ((r * (r - 1)) >> 1);
}

// ---------------- embed: x @ W_embed + b + pos, LIF ----------------
__global__ __launch_bounds__(256) void embed_kernel(
    const float* __restrict__ x, const float* __restrict__ We,
    const float* __restrict__ be, const float* __restrict__ pos,
    float* __restrict__ xemb) {
    int tok = blockIdx.x;
    int d = threadIdx.x;
    __shared__ float xs[240];
    if (d < 240) xs[d] = x[(size_t)tok * 240 + d];
    __syncthreads();
    int r = tok % 90;
    double acc = 0.0;
    for (int s = 0; s < 240; ++s)
        acc = fma((double)xs[s], (double)We[(size_t)s * 256 + d], acc);
    float a = (float)acc + be[d] + pos[r * 256 + d];
    xemb[(size_t)tok * 256 + d] = (a > 1.0f) ? 1.0f : 0.0f;
}

// ---------------- simple copy / zero ----------------
__global__ void copy_kernel(float* __restrict__ dst, const float* __restrict__ src, int n) {
    int i = blockIdx.x * 256 + threadIdx.x;
    if (i < n) dst[i] = src[i];
}
__global__ void zero_kernel(float* __restrict__ p, int n) {
    int i = blockIdx.x * 256 + threadIdx.x;
    if (i < n) p[i] = 0.f;
}

// ---------------- LayerNorm, split weight select (row<split -> set A) ----------------
__global__ __launch_bounds__(256) void ln_kernel(
    const float* __restrict__ X,
    const float* __restrict__ gA, const float* __restrict__ bA,
    const float* __restrict__ gB, const float* __restrict__ bB,
    int split, float* __restrict__ Y) {
    int row = blockIdx.x;
    int d = threadIdx.x;
    const float* g = (row < split) ? gA : gB;
    const float* b = (row < split) ? bA : bB;
    __shared__ float red[256];
    float v = X[(size_t)row * 256 + d];
    red[d] = v;
    __syncthreads();
    for (int s = 128; s > 0; s >>= 1) { if (d < s) red[d] += red[d + s]; __syncthreads(); }
    float mean = red[0] * (1.0f / 256.0f);
    __syncthreads();
    float dv = v - mean;
    red[d] = dv * dv;
    __syncthreads();
    for (int s = 128; s > 0; s >>= 1) { if (d < s) red[d] += red[d + s]; __syncthreads(); }
    float var = red[0] * (1.0f / 256.0f);
    float r = 1.0f / sqrtf(var + 1e-5f);
    Y[(size_t)row * 256 + d] = dv * r * g[d] + b[d];
}

// ---------------- final LN + LIF ----------------
__global__ __launch_bounds__(256) void ln_lif_kernel(
    const float* __restrict__ X, const float* __restrict__ g, const float* __restrict__ b,
    float* __restrict__ Y) {
    int row = blockIdx.x;
    int d = threadIdx.x;
    __shared__ float red[256];
    float v = X[(size_t)row * 256 + d];
    red[d] = v;
    __syncthreads();
    for (int s = 128; s > 0; s >>= 1) { if (d < s) red[d] += red[d + s]; __syncthreads(); }
    float mean = red[0] * (1.0f / 256.0f);
    __syncthreads();
    float dv = v - mean;
    red[d] = dv * dv;
    __syncthreads();
    for (int s = 128; s > 0; s >>= 1) { if (d < s) red[d] += red[d + s]; __syncthreads(); }
    float var = red[0] * (1.0f / 256.0f);
    float r = 1.0f / sqrtf(var + 1e-5f);
    float val = dv * r * g[d] + b[d];
    Y[(size_t)row * 256 + d] = (val > 1.0f) ? 1.0f : 0.0f;
}

// ---------------- GEMM 64x64, BK=32, double-buffered (tall-M path) ----------------
// Bit-exact ascending-k fmaf chain. EPI 0: store; 1: acc+R; 2: gelu(acc)
template <int EPI>
__global__ __launch_bounds__(256) void gemm_kernel(
    const float* __restrict__ A, const float* __restrict__ W0,
    const float* __restrict__ W1, int wsplit,
    float* __restrict__ C, const float* __restrict__ R,
    int M, int N, int K, int ldA, int ldW, int ldC,
    int zA, int zW, long zC) {
    __shared__ float As[2][32][64 + 4];
    __shared__ float Ws[2][32][64];
    int bm = blockIdx.y * 64;
    int bn = blockIdx.x * 64;
    int z = blockIdx.z;
    A += (size_t)z * zA;
    const float* W = ((bm < wsplit) ? W0 : W1) + (size_t)z * zW;
    C += (size_t)z * zC;
    const float* Rp = R + (size_t)z * zC;
    int tid = threadIdx.x;
    int tx = tid & 15;
    int ty = tid >> 4;
    int ar = tid >> 2;            // 0..63 A row
    int ak = (tid & 3) * 8;       // 0,8,16,24
    int wk = tid >> 3;            // 0..31 W k-row
    int wn = (tid & 7) * 8;       // 0..56
    int gm = bm + ar;
    bool aok = gm < M;
    const float* Aptr = A + (size_t)gm * ldA + ak;
    const float* Wptr = W + (size_t)wk * ldW + bn + wn;

    float acc[4][4] = {{0.f}};
    float4 va0 = make_float4(0.f,0.f,0.f,0.f), va1 = va0;
    if (aok) { va0 = *(const float4*)Aptr; va1 = *(const float4*)(Aptr + 4); }
    float4 vw0 = *(const float4*)Wptr;
    float4 vw1 = *(const float4*)(Wptr + 4);
    As[0][ak + 0][ar] = va0.x; As[0][ak + 1][ar] = va0.y;
    As[0][ak + 2][ar] = va0.z; As[0][ak + 3][ar] = va0.w;
    As[0][ak + 4][ar] = va1.x; As[0][ak + 5][ar] = va1.y;
    As[0][ak + 6][ar] = va1.z; As[0][ak + 7][ar] = va1.w;
    *(float4*)&Ws[0][wk][wn] = vw0;
    *(float4*)&Ws[0][wk][wn + 4] = vw1;
    __syncthreads();

    int nt = K / 32;
    for (int t = 0; t < nt; ++t) {
        int cur = t & 1;
        if (t + 1 < nt) {
            if (aok) {
                va0 = *(const float4*)(Aptr + (t + 1) * 32);
                va1 = *(const float4*)(Aptr + (t + 1) * 32 + 4);
            }
            vw0 = *(const float4*)(Wptr + (size_t)(t + 1) * 32 * ldW);
            vw1 = *(const float4*)(Wptr + (size_t)(t + 1) * 32 * ldW + 4);
        }
        #pragma unroll
        for (int k = 0; k < 32; ++k) {
            float a[4], w[4];
            #pragma unroll
            for (int i = 0; i < 4; ++i) a[i] = As[cur][k][ty * 4 + i];
            #pragma unroll
            for (int j = 0; j < 4; ++j) w[j] = Ws[cur][k][tx * 4 + j];
            #pragma unroll
            for (int i = 0; i < 4; ++i)
                #pragma unroll
                for (int j = 0; j < 4; ++j)
                    acc[i][j] = fmaf(a[i], w[j], acc[i][j]);
        }
        if (t + 1 < nt) {
            int nx = cur ^ 1;
            As[nx][ak + 0][ar] = va0.x; As[nx][ak + 1][ar] = va0.y;
            As[nx][ak + 2][ar] = va0.z; As[nx][ak + 3][ar] = va0.w;
            As[nx][ak + 4][ar] = va1.x; As[nx][ak + 5][ar] = va1.y;
            As[nx][ak + 6][ar] = va1.z; As[nx][ak + 7][ar] = va1.w;
            *(float4*)&Ws[nx][wk][wn] = vw0;
            *(float4*)&Ws[nx][wk][wn + 4] = vw1;
        }
        __syncthreads();
    }
    #pragma unroll
    for (int i = 0; i < 4; ++i) {
        int om = bm + ty * 4 + i;
        if (om >= M) continue;
        #pragma unroll
        for (int j = 0; j < 4; ++j) {
            int on = bn + tx * 4 + j;
            float v = acc[i][j];
            if (EPI == 1) v += Rp[(size_t)om * ldC + on];
            if (EPI == 2) v = gelu_f(v);
            C[(size_t)om * ldC + on] = v;
        }
    }
}

// ---------------- GEMM 32x64, BK=16, 128 threads (small-M path) ----------------
// Same ascending-k fmaf chain; more blocks in flight for small M.
template <int EPI>
__global__ __launch_bounds__(128) void gemm_small_kernel(
    const float* __restrict__ A, const float* __restrict__ W0,
    const float* __restrict__ W1, int wsplit,
    float* __restrict__ C, const float* __restrict__ R,
    int M, int N, int K, int ldA, int ldW, int ldC,
    int zA, int zW, long zC) {
    __shared__ float As[16][32 + 4];
    __shared__ float Ws[16][64];
    int bm = blockIdx.y * 32;
    int bn = blockIdx.x * 64;
    int z = blockIdx.z;
    A += (size_t)z * zA;
    const float* W = ((bm < wsplit) ? W0 : W1) + (size_t)z * zW;
    C += (size_t)z * zC;
    const float* Rp = R + (size_t)z * zC;
    int tid = threadIdx.x;
    int tx = tid & 15;   // n-dir
    int ty = tid >> 4;   // 0..7 m-dir
    float acc[4][4] = {{0.f}};
    int ar = tid >> 2;           // 0..31
    int ak = (tid & 3) * 4;      // 0,4,8,12
    int wk = tid >> 3;           // 0..15
    int wn = (tid & 7) * 8;      // 0..56
    for (int k0 = 0; k0 < K; k0 += 16) {
        {
            int gm = bm + ar;
            float4 v = make_float4(0.f, 0.f, 0.f, 0.f);
            if (gm < M) v = *(const float4*)(A + (size_t)gm * ldA + k0 + ak);
            As[ak + 0][ar] = v.x; As[ak + 1][ar] = v.y;
            As[ak + 2][ar] = v.z; As[ak + 3][ar] = v.w;
        }
        {
            const float* p = W + (size_t)(k0 + wk) * ldW + bn + wn;
            float4 v0 = *(const float4*)p;
            float4 v1 = *(const float4*)(p + 4);
            *(float4*)&Ws[wk][wn] = v0;
            *(float4*)&Ws[wk][wn + 4] = v1;
        }
        __syncthreads();
        #pragma unroll
        for (int k = 0; k < 16; ++k) {
            float a[4], w[4];
            #pragma unroll
            for (int i = 0; i < 4; ++i) a[i] = As[k][ty * 4 + i];
            #pragma unroll
            for (int j = 0; j < 4; ++j) w[j] = Ws[k][tx * 4 + j];
            #pragma unroll
            for (int i = 0; i < 4; ++i)
                #pragma unroll
                for (int j = 0; j < 4; ++j)
                    acc[i][j] = fmaf(a[i], w[j], acc[i][j]);
        }
        __syncthreads();
    }
    #pragma unroll
    for (int i = 0; i < 4; ++i) {
        int gm = bm + ty * 4 + i;
        if (gm >= M) continue;
        #pragma unroll
        for (int j = 0; j < 4; ++j) {
            int gn = bn + tx * 4 + j;
            float v = acc[i][j];
            if (EPI == 1) v += Rp[(size_t)gm * ldC + gn];
            if (EPI == 2) v = gelu_f(v);
            C[(size_t)gm * ldC + gn] = v;
        }
    }
}

// ---------------- ordered FF accumulate: X = (((X+S0)+S1)+S2)+S3 ----------------
__global__ void addff_kernel(float4* __restrict__ X, const float4* __restrict__ S,
                             long zstr4, int n4) {
    int i = blockIdx.x * 256 + threadIdx.x;
    if (i >= n4) return;
    float4 x = X[i];
    float4 s0 = S[i], s1 = S[i + zstr4], s2 = S[i + 2 * zstr4], s3 = S[i + 3 * zstr4];
    x.x = (((x.x + s0.x) + s1.x) + s2.x) + s3.x;
    x.y = (((x.y + s0.y) + s1.y) + s2.y) + s3.y;
    x.z = (((x.z + s0.z) + s1.z) + s2.z) + s3.z;
    x.w = (((x.w + s0.w) + s1.w) + s2.w) + s3.w;
    X[i] = x;
}

// ---------------- attention: grid (seq, head); token base split for co-batch ----------------
__global__ __launch_bounds__(128) void attn_kernel(
    const float* __restrict__ QKV, float* __restrict__ AO,
    int N, int causal, int hs, int off2) {
    int s = blockIdx.x, h = blockIdx.y;
    int tokbase = (s < hs) ? s * N : off2 + (s - hs) * N;
    __shared__ float Ks[90][32];
    __shared__ float Vs[90][32];
    int tid = threadIdx.x;
    for (int i = tid; i < N * 32; i += 128) {
        int n = i >> 5, d = i & 31;
        size_t base = ((size_t)(tokbase + n)) * 768 + h * 32;
        Ks[n][d] = QKV[base + 256 + d];
        Vs[n][d] = QKV[base + 512 + d];
    }
    __syncthreads();
    int q = tid;
    if (q >= N) return;
    float qv[32];
    size_t qbase = ((size_t)(tokbase + q)) * 768 + h * 32;
    #pragma unroll
    for (int d = 0; d < 32; ++d) qv[d] = QKV[qbase + d];
    const float sq = 5.656854249492380195f;
    int kmax = causal ? (q + 1) : N;
    float m = -3.0e38f;
    for (int k = 0; k < kmax; ++k) {
        float sd = 0.f;
        #pragma unroll
        for (int d = 0; d < 32; ++d) sd = fmaf(qv[d], Ks[k][d], sd);
        sd /= sq;
        m = fmaxf(m, sd);
    }
    float sum = 0.f;
    float acc[32];
    #pragma unroll
    for (int d = 0; d < 32; ++d) acc[d] = 0.f;
    for (int k = 0; k < kmax; ++k) {
        float sd = 0.f;
        #pragma unroll
        for (int d = 0; d < 32; ++d) sd = fmaf(qv[d], Ks[k][d], sd);
        sd /= sq;
        float p = expf(sd - m);
        sum += p;
        #pragma unroll
        for (int d = 0; d < 32; ++d) acc[d] = fmaf(p, Vs[k][d], acc[d]);
    }
    size_t obase = ((size_t)(tokbase + q)) * 256 + h * 32;
    #pragma unroll
    for (int d = 0; d < 32; ++d) AO[obase + d] = acc[d] / sum;
}

// ---------------- suffix attention (kv cache prefix + own suffix) ----------------
__global__ __launch_bounds__(128) void suffix_attn_kernel(
    const float* __restrict__ QKV, const float* __restrict__ kv,
    float* __restrict__ AO, int g0) {
    int ls = blockIdx.x, h = blockIdx.y;
    int g = g0 + ls;
    int b = g / 90, r = g - b * 90;
    int toff = suffix_off(g) - suffix_off(g0);
    int L = 90 - r;
    __shared__ float Ks[90][32];
    __shared__ float Vs[90][32];
    int tid = threadIdx.x;
    for (int i = tid; i < 90 * 32; i += 128) {
        int p = i >> 5, d = i & 31;
        float kk, vv;
        if (p < r) {
            const float* src = kv + ((size_t)(b * 89 + p)) * 512 + h * 32 + d;
            kk = src[0]; vv = src[256];
        } else {
            size_t base = ((size_t)(toff + p - r)) * 768 + h * 32 + d;
            kk = QKV[base + 256]; vv = QKV[base + 512];
        }
        Ks[p][d] = kk; Vs[p][d] = vv;
    }
    __syncthreads();
    if (tid >= L) return;
    int jq = r + tid;
    float qv[32];
    size_t qbase = ((size_t)(toff + tid)) * 768 + h * 32;
    #pragma unroll
    for (int d = 0; d < 32; ++d) qv[d] = QKV[qbase + d];
    const float sq = 5.656854249492380195f;
    int kmax = jq + 1;
    float m = -3.0e38f;
    for (int k = 0; k < kmax; ++k) {
        float sd = 0.f;
        #pragma unroll
        for (int d = 0; d < 32; ++d) sd = fmaf(qv[d], Ks[k][d], sd);
        sd /= sq;
        m = fmaxf(m, sd);
    }
    float sum = 0.f;
    float acc[32];
    #pragma unroll
    for (int d = 0; d < 32; ++d) acc[d] = 0.f;
    for (int k = 0; k < kmax; ++k) {
        float sd = 0.f;
        #pragma unroll
        for (int d = 0; d < 32; ++d) sd = fmaf(qv[d], Ks[k][d], sd);
        sd /= sq;
        float p = expf(sd - m);
        sum += p;
        #pragma unroll
        for (int d = 0; d < 32; ++d) acc[d] = fmaf(p, Vs[k][d], acc[d]);
    }
    size_t obase = ((size_t)(toff + tid)) * 256 + h * 32;
    #pragma unroll
    for (int d = 0; d < 32; ++d) AO[obase + d] = acc[d] / sum;
}

// ---------------- last-query-only suffix attention (layer 6) ----------------
__global__ __launch_bounds__(128) void lastq_attn_kernel(
    const float* __restrict__ QKV, const float* __restrict__ kv,
    float* __restrict__ AO2, int g0) {
    int ls = blockIdx.x, h = blockIdx.y;
    int g = g0 + ls;
    int b = g / 90, r = g - b * 90;
    int toff = suffix_off(g) - suffix_off(g0);
    int L = 90 - r;
    __shared__ float Ks[90][32];
    __shared__ float Vs[90][32];
    int tid = threadIdx.x;
    for (int i = tid; i < 90 * 32; i += 128) {
        int p = i >> 5, d = i & 31;
        float kk, vv;
        if (p < r) {
            const float* src = kv + ((size_t)(b * 89 + p)) * 512 + h * 32 + d;
            kk = src[0]; vv = src[256];
        } else {
            size_t base = ((size_t)(toff + p - r)) * 768 + h * 32 + d;
            kk = QKV[base + 256]; vv = QKV[base + 512];
        }
        Ks[p][d] = kk; Vs[p][d] = vv;
    }
    __syncthreads();
    if (tid != 0) return;
    float qv[32];
    size_t qbase = ((size_t)(toff + L - 1)) * 768 + h * 32;   // query jq = 89
    #pragma unroll
    for (int d = 0; d < 32; ++d) qv[d] = QKV[qbase + d];
    const float sq = 5.656854249492380195f;
    float m = -3.0e38f;
    for (int k = 0; k < 90; ++k) {
        float sd = 0.f;
        #pragma unroll
        for (int d = 0; d < 32; ++d) sd = fmaf(qv[d], Ks[k][d], sd);
        sd /= sq;
        m = fmaxf(m, sd);
    }
    float sum = 0.f;
    float acc[32];
    #pragma unroll
    for (int d = 0; d < 32; ++d) acc[d] = 0.f;
    for (int k = 0; k < 90; ++k) {
        float sd = 0.f;
        #pragma unroll
        for (int d = 0; d < 32; ++d) sd = fmaf(qv[d], Ks[k][d], sd);
        sd /= sq;
        float p = expf(sd - m);
        sum += p;
        #pragma unroll
        for (int d = 0; d < 32; ++d) acc[d] = fmaf(p, Vs[k][d], acc[d]);
    }
    size_t obase = (size_t)ls * 256 + h * 32;
    #pragma unroll
    for (int d = 0; d < 32; ++d) AO2[obase + d] = acc[d] / sum;
}

// ---------------- masks = lif(mask_token + pos) ----------------
__global__ void masks_kernel(const float* __restrict__ mt, const float* __restrict__ pos,
                             float* __restrict__ M) {
    int i = blockIdx.x * 256 + threadIdx.x;
    if (i >= 90 * 256) return;
    int d = i & 255;
    float v = mt[d] + pos[i];
    M[i] = (v > 1.0f) ? 1.0f : 0.0f;
}

// ---------------- canonical gather (batch chunk at b0) ----------------
__global__ __launch_bounds__(256) void gather_canon_kernel(
    const float* __restrict__ student, float* __restrict__ Xc, int b0) {
    int tc = blockIdx.x;
    int d = threadIdx.x;
    int b = b0 + tc / 89, p = tc % 89;
    Xc[(size_t)tc * 256 + d] = student[((size_t)(b * 90 + p)) * 256 + d];
}

// ---------------- cache canonical K/V (batch chunk at b0) ----------------
__global__ __launch_bounds__(256) void kvcopy_kernel(
    const float* __restrict__ QKVc, float* __restrict__ kvl, int b0) {
    int tc = blockIdx.x;
    int c = threadIdx.x;
    size_t gtc = (size_t)b0 * 89 + tc;
    kvl[gtc * 512 + c]       = QKVc[(size_t)tc * 768 + 256 + c];
    kvl[gtc * 512 + 256 + c] = QKVc[(size_t)tc * 768 + 512 + c];
}

// ---------------- gather suffix tokens for seq chunk [g0, g0+c) ----------------
__global__ __launch_bounds__(256) void gather_suffix_kernel(
    const float* __restrict__ student, const float* __restrict__ masks,
    float* __restrict__ X, int g0) {
    int ls = blockIdx.x, slot = blockIdx.y;
    int d = threadIdx.x;
    int g = g0 + ls;
    int b = g / 90, r = g - b * 90;
    if (slot >= 90 - r) return;
    int j = r + slot;
    int dst = suffix_off(g) - suffix_off(g0) + slot;
    float v;
    if (j == 89) v = masks[r * 256 + d];
    else         v = student[((size_t)(b * 90 + j + 1)) * 256 + d];
    X[(size_t)dst * 256 + d] = v;
}

// ---------------- gather last-token residual rows ----------------
__global__ __launch_bounds__(256) void gather_last_kernel(
    const float* __restrict__ X, float* __restrict__ X2, int g0) {
    int ls = blockIdx.x;
    int d = threadIdx.x;
    int g = g0 + ls;
    int r = g % 90;
    int tok = suffix_off(g) - suffix_off(g0) + (89 - r);
    X2[(size_t)ls * 256 + d] = X[(size_t)tok * 256 + d];
}

// ---------------- LIF rows -> predT ----------------
__global__ __launch_bounds__(256) void lif_rows_kernel(
    const float* __restrict__ X2, float* __restrict__ predT, int g0) {
    int ls = blockIdx.x;
    int d = threadIdx.x;
    float v = X2[(size_t)ls * 256 + d];
    predT[(size_t)(g0 + ls) * 256 + d] = (v > 1.0f) ? 1.0f : 0.0f;
}

// ---------------- decode: lif(T @ W_dec + b_dec) + row mean ----------------
__global__ __launch_bounds__(256) void decode_kernel(
    const float* __restrict__ T, const float* __restrict__ Wd, const float* __restrict__ bd,
    float* __restrict__ outseq, float* __restrict__ outmean) {
    int row = blockIdx.x;
    int n = threadIdx.x;
    __shared__ float ts[256];
    __shared__ float red[256];
    ts[n] = T[(size_t)row * 256 + n];
    __syncthreads();
    float sval = 0.f;
    if (n < 240) {
        double acc = 0.0;
        for (int k = 0; k < 256; ++k)
            acc = fma((double)ts[k], (double)Wd[(size_t)k * 240 + n], acc);
        float a = (float)acc;
        a += bd[n];
        sval = (a > 1.0f) ? 1.0f : 0.0f;
        outseq[(size_t)row * 240 + n] = sval;
    }
    red[n] = sval;
    __syncthreads();
    for (int s = 128; s > 0; s >>= 1) { if (n < s) red[n] += red[n + s]; __syncthreads(); }
    if (n == 0) outmean[row] = red[0] * (1.0f / 240.0f);
}

// ---------------- target passthrough + mean ----------------
__global__ __launch_bounds__(256) void target_kernel(
    const float* __restrict__ x, float* __restrict__ outseq, float* __restrict__ outmean) {
    int row = blockIdx.x;
    int n = threadIdx.x;
    __shared__ float red[256];
    float v = 0.f;
    if (n < 240) {
        v = x[(size_t)row * 240 + n];
        outseq[(size_t)row * 240 + n] = v;
    }
    red[n] = v;
    __syncthreads();
    for (int s = 128; s > 0; s >>= 1) { if (n < s) red[n] += red[n + s]; __syncthreads(); }
    if (n == 0) outmean[row] = red[0] * (1.0f / 240.0f);
}

// ---------------- host ----------------
extern "C" void kernel_launch(void* const* d_in, const int* in_sizes, int n_in,
                              void* d_out, int out_size, void* d_ws, size_t ws_size,
                              hipStream_t stream) {
    const float* x   = (const float*)d_in[0];
    const float* We  = (const float*)d_in[1];
    const float* be  = (const float*)d_in[2];
    const float* pos = (const float*)d_in[3];
    const float* mt  = (const float*)d_in[4];
    const float* ng  = (const float*)d_in[5];
    const float* nb  = (const float*)d_in[6];
    const float* Wd  = (const float*)d_in[7];
    const float* bd  = (const float*)d_in[8];
    const float* prm[3][6];
    for (int g = 0; g < 3; ++g)
        for (int k = 0; k < 6; ++k)
            prm[g][k] = (const float*)d_in[9 + g * 6 + k];

    float* wp = (float*)d_ws;
    auto alloc = [&](size_t n) { float* q = wp; wp += n; return q; };
    float* x_emb   = alloc(720 * 256);
    float* teacher = alloc(720 * 256);
    float* student = alloc(720 * 256);
    float* predT   = alloc(720 * 256);
    float* masksb  = alloc(90 * 256);
    float* kvc     = alloc(6ull * 712 * 512);
    float* AO2 = alloc(720 * 256);
    float* X2  = alloc(720 * 256);
    float* Xn2 = alloc(720 * 256);
    float* H2  = alloc(720 * 1024);
    float* S2  = alloc(4ull * 720 * 256);
    long  zS2  = 720 * 256;
    size_t fixed = (size_t)(wp - (float*)d_ws);

    size_t avail = ws_size / 4;
    long tcap_l = 90;
    if (avail > fixed) {
        long t = (long)((avail - fixed) / 3328);
        if (t > tcap_l) tcap_l = t;
    }
    if (tcap_l > 32760) tcap_l = 32760;
    int TCAP = (int)tcap_l;
    float* X   = alloc((size_t)TCAP * 256);
    float* Xn  = alloc((size_t)TCAP * 256);
    float* QKV = alloc((size_t)TCAP * 768);
    float* H   = alloc((size_t)TCAP * 1024);
    float* S   = alloc(4ull * TCAP * 256);
    long  zS   = (long)TCAP * 256;
    bool co_batch = (TCAP >= 1488);

    float* out = (float*)d_out;
    const int NOSPLIT = 1 << 30;

    embed_kernel<<<720, 256, 0, stream>>>(x, We, be, pos, x_emb);
    masks_kernel<<<90, 256, 0, stream>>>(mt, pos, masksb);

    // dispatch: tall-M -> 64x64 BK32 dbuf; small-M -> 32x64 (wide grid)
    auto launch_gemm = [&](int epi, const float* A, const float* W0, const float* W1,
                           int wsplit, float* C, const float* R, int M, int N, int K,
                           int ldA, int ldW, int ldC, int zA, int zW, long zC, int nz) {
        if (M >= 2048) {
            dim3 g(N / 64, (M + 63) / 64, nz);
            if (epi == 0) gemm_kernel<0><<<g, 256, 0, stream>>>(A, W0, W1, wsplit, C, R, M, N, K, ldA, ldW, ldC, zA, zW, zC);
            if (epi == 1) gemm_kernel<1><<<g, 256, 0, stream>>>(A, W0, W1, wsplit, C, R, M, N, K, ldA, ldW, ldC, zA, zW, zC);
            if (epi == 2) gemm_kernel<2><<<g, 256, 0, stream>>>(A, W0, W1, wsplit, C, R, M, N, K, ldA, ldW, ldC, zA, zW, zC);
        } else {
            dim3 g(N / 64, (M + 31) / 32, nz);
            if (epi == 0) gemm_small_kernel<0><<<g, 128, 0, stream>>>(A, W0, W1, wsplit, C, R, M, N, K, ldA, ldW, ldC, zA, zW, zC);
            if (epi == 1) gemm_small_kernel<1><<<g, 128, 0, stream>>>(A, W0, W1, wsplit, C, R, M, N, K, ldA, ldW, ldC, zA, zW, zC);
            if (epi == 2) gemm_small_kernel<2><<<g, 128, 0, stream>>>(A, W0, W1, wsplit, C, R, M, N, K, ldA, ldW, ldC, zA, zW, zC);
        }
    };

    auto run_layer = [&](int T, int gA, int gB, int l, int split, auto&& attn_launch) {
        const float* qkvA = prm[gA][0] + (size_t)l * 256 * 768;
        const float* qkvB = prm[gB][0] + (size_t)l * 256 * 768;
        const float* woA  = prm[gA][1] + (size_t)l * 256 * 256;
        const float* woB  = prm[gB][1] + (size_t)l * 256 * 256;
        const float* l1A  = prm[gA][2] + (size_t)l * 512;
        const float* l1B  = prm[gB][2] + (size_t)l * 512;
        const float* f1A  = prm[gA][3] + (size_t)l * 256 * 1024;
        const float* f1B  = prm[gB][3] + (size_t)l * 256 * 1024;
        const float* f2A  = prm[gA][4] + (size_t)l * 1024 * 256;
        const float* f2B  = prm[gB][4] + (size_t)l * 1024 * 256;
        const float* l2A  = prm[gA][5] + (size_t)l * 512;
        const float* l2B  = prm[gB][5] + (size_t)l * 512;
        ln_kernel<<<T, 256, 0, stream>>>(X, l1A, l1A + 256, l1B, l1B + 256, split, Xn);
        launch_gemm(0, Xn, qkvA, qkvB, split, QKV, QKV, T, 768, 256, 256, 768, 768, 0, 0, 0, 1);
        attn_launch();
        launch_gemm(1, Xn, woA, woB, split, X, X, T, 256, 256, 256, 256, 256, 0, 0, 0, 1);
        ln_kernel<<<T, 256, 0, stream>>>(X, l2A, l2A + 256, l2B, l2B + 256, split, Xn);
        launch_gemm(2, Xn, f1A, f1B, split, H, H, T, 1024, 256, 256, 1024, 1024, 0, 0, 0, 1);
        launch_gemm(0, H, f2A, f2B, split, S, S, T, 256, 256, 1024, 256, 256, 256, 65536, zS, 4);
        addff_kernel<<<(T * 64 + 255) / 256, 256, 0, stream>>>(
            (float4*)X, (const float4*)S, zS / 4, T * 64);
    };

    // ---- encoders ----
    if (co_batch) {
        copy_kernel<<<720, 256, 0, stream>>>(X, x_emb, 720 * 256);
        copy_kernel<<<720, 256, 0, stream>>>(X + 768 * 256, x_emb, 720 * 256);
        zero_kernel<<<48, 256, 0, stream>>>(X + 720 * 256, 48 * 256);
        for (int l = 0; l < 8; ++l)
            run_layer(1488, 0, 1, l, 768,
                      [&] { attn_kernel<<<dim3(16, 8), 128, 0, stream>>>(
                                QKV, Xn, 90, 0, 8, 768); });
        ln_lif_kernel<<<720, 256, 0, stream>>>(X, ng, nb, teacher);
        ln_lif_kernel<<<720, 256, 0, stream>>>(X + 768 * 256, ng, nb, student);
    } else {
        int ce = TCAP / 90; if (ce > 8) ce = 8; if (ce < 1) ce = 1;
        for (int gi = 0; gi < 2; ++gi) {
            for (int s0 = 0; s0 < 8; s0 += ce) {
                int c = (8 - s0) < ce ? (8 - s0) : ce;
                int T = c * 90;
                copy_kernel<<<(T * 256 + 255) / 256, 256, 0, stream>>>(
                    X, x_emb + (size_t)s0 * 90 * 256, T * 256);
                for (int l = 0; l < 8; ++l)
                    run_layer(T, gi, gi, l, NOSPLIT,
                              [&] { attn_kernel<<<dim3(c, 8), 128, 0, stream>>>(
                                        QKV, Xn, 90, 0, c, 0); });
                ln_lif_kernel<<<T, 256, 0, stream>>>(
                    X, ng, nb, (gi == 0 ? teacher : student) + (size_t)s0 * 90 * 256);
            }
        }
    }

    // ---- predictor phase 1: canonical prefixes, cache K/V per layer ----
    {
        int cb = TCAP / 89; if (cb > 8) cb = 8; if (cb < 1) cb = 1;
        for (int b0 = 0; b0 < 8; b0 += cb) {
            int c = (8 - b0) < cb ? (8 - b0) : cb;
            int T = c * 89;
            gather_canon_kernel<<<T, 256, 0, stream>>>(student, X, b0);
            for (int l = 0; l < 5; ++l) {
                float* kvl = kvc + (size_t)l * 712 * 512;
                run_layer(T, 2, 2, l, NOSPLIT,
                          [&] {
                              kvcopy_kernel<<<T, 256, 0, stream>>>(QKV, kvl, b0);
                              attn_kernel<<<dim3(c, 8), 128, 0, stream>>>(
                                  QKV, Xn, 89, 1, c, 0);
                          });
            }
            {   // l = 5: ln1 + qkv + kvcopy only
                const float* l1P  = prm[2][2] + 5ull * 512;
                const float* qkvP = prm[2][0] + 5ull * 256 * 768;
                float* kvl = kvc + 5ull * 712 * 512;
                ln_kernel<<<T, 256, 0, stream>>>(X, l1P, l1P + 256, l1P, l1P + 256,
                                                 NOSPLIT, Xn);
                launch_gemm(0, Xn, qkvP, qkvP, NOSPLIT, QKV, QKV, T, 768, 256, 256, 768, 768, 0, 0, 0, 1);
                kvcopy_kernel<<<T, 256, 0, stream>>>(QKV, kvl, b0);
            }
        }
    }

    // ---- predictor phase 2: suffixes, chunked; layer 6 pruned to last tokens ----
    auto Toff = [](int g) { int b = g / 90, r = g - b * 90;
                            return (long)b * 4095 + 90L * r - (long)r * (r - 1) / 2; };
    int cs = TCAP / 90; if (cs < 1) cs = 1; if (cs > 720) cs = 720;
    for (int g0 = 0; g0 < 720; ) {
        int g1 = g0 + cs; if (g1 > 720) g1 = 720;
        while ((int)(Toff(g1) - Toff(g0)) > TCAP && g1 > g0 + 1) --g1;
        int c = g1 - g0;
        int Tc = (int)(Toff(g1) - Toff(g0));
        { dim3 g(c, 90);
          gather_suffix_kernel<<<g, 256, 0, stream>>>(student, masksb, X, g0); }
        for (int l = 0; l < 5; ++l) {
            float* kvl = kvc + (size_t)l * 712 * 512;
            run_layer(Tc, 2, 2, l, NOSPLIT,
                      [&] { dim3 g(c, 8);
                            suffix_attn_kernel<<<g, 128, 0, stream>>>(QKV, kvl, Xn, g0); });
        }
        {   // l = 5: full ln1+qkv (K/V needed), then last-token-only tail
            const float* qkvP = prm[2][0] + 5ull * 256 * 768;
            const float* woP  = prm[2][1] + 5ull * 256 * 256;
            const float* l1P  = prm[2][2] + 5ull * 512;
            const float* f1P  = prm[2][3] + 5ull * 256 * 1024;
            const float* f2P  = prm[2][4] + 5ull * 1024 * 256;
            const float* l2P  = prm[2][5] + 5ull * 512;
            float* kvl = kvc + 5ull * 712 * 512;
            ln_kernel<<<Tc, 256, 0, stream>>>(X, l1P, l1P + 256, l1P, l1P + 256,
                                              NOSPLIT, Xn);
            launch_gemm(0, Xn, qkvP, qkvP, NOSPLIT, QKV, QKV, Tc, 768, 256, 256, 768, 768, 0, 0, 0, 1);
            { dim3 g(c, 8);
              lastq_attn_kernel<<<g, 128, 0, stream>>>(QKV, kvl, AO2, g0); }
            gather_last_kernel<<<c, 256, 0, stream>>>(X, X2, g0);
            launch_gemm(1, AO2, woP, woP, NOSPLIT, X2, X2, c, 256, 256, 256, 256, 256, 0, 0, 0, 1);
            ln_kernel<<<c, 256, 0, stream>>>(X2, l2P, l2P + 256, l2P, l2P + 256,
                                             NOSPLIT, Xn2);
            launch_gemm(2, Xn2, f1P, f1P, NOSPLIT, H2, H2, c, 1024, 256, 256, 1024, 1024, 0, 0, 0, 1);
            launch_gemm(0, H2, f2P, f2P, NOSPLIT, S2, S2, c, 256, 256, 1024, 256, 256, 256, 65536, zS2, 4);
            addff_kernel<<<(c * 64 + 255) / 256, 256, 0, stream>>>(
                (float4*)X2, (const float4*)S2, zS2 / 4, c * 64);
            lif_rows_kernel<<<c, 256, 0, stream>>>(X2, predT, g0);
        }
        g0 = g1;
    }

    decode_kernel<<<720, 256, 0, stream>>>(predT, Wd, bd, out + 0, out + 518400);
    decode_kernel<<<720, 256, 0, stream>>>(teacher, Wd, bd, out + 172800, out + 519120);
    target_kernel<<<720, 256, 0, stream>>>(x, out + 345600, out + 519840);
}

// Round 10
// 9889.040 us; speedup vs baseline: 1.3120x; 1.3120x over previous
//
#include <hip/hip_runtime.h>
#include <math.h>

// NOTE: binary spike outputs require BIT-EXACT reproduction of the validated
// reduction orders (rounds 2/5/6/8). GEMM = round-8 validated 64x64 BK16
// double-buffered kernel (round-9's BK32/small-M variants REGRESSED; reverted).
// New this round: ff2 fused kernel — identical per-256-k ascending fmaf chains
// into separate accumulators, folded as (((X+S0)+S1)+S2)+S3 in the exact old
// order at each 256-k boundary. Bit-exact; removes S buffers + addff pass.

// ---------------- device helpers ----------------
__device__ __forceinline__ float gelu_f(float x) {
    const float c = 0.7978845608028654f; // sqrt(2/pi)
    float x3 = x * x * x;
    float inner = c * (x + 0.044715f * x3);
    return 0.5f * x * (1.0f + tanhf(inner));
}

__device__ __forceinline__ int suffix_off(int g) {
    int b = g / 90, r = g - b * 90;
    return b * 4095 + 90 * r - ((r * (r - 1)) >> 1);
}

// ---------------- embed: x @ W_embed + b + pos, LIF ----------------
__global__ __launch_bounds__(256) void embed_kernel(
    const float* __restrict__ x, const float* __restrict__ We,
    const float* __restrict__ be, const float* __restrict__ pos,
    float* __restrict__ xemb) {
    int tok = blockIdx.x;
    int d = threadIdx.x;
    __shared__ float xs[240];
    if (d < 240) xs[d] = x[(size_t)tok * 240 + d];
    __syncthreads();
    int r = tok % 90;
    double acc = 0.0;
    for (int s = 0; s < 240; ++s)
        acc = fma((double)xs[s], (double)We[(size_t)s * 256 + d], acc);
    float a = (float)acc + be[d] + pos[r * 256 + d];
    xemb[(size_t)tok * 256 + d] = (a > 1.0f) ? 1.0f : 0.0f;
}

// ---------------- simple copy / zero ----------------
__global__ void copy_kernel(float* __restrict__ dst, const float* __restrict__ src, int n) {
    int i = blockIdx.x * 256 + threadIdx.x;
    if (i < n) dst[i] = src[i];
}
__global__ void zero_kernel(float* __restrict__ p, int n) {
    int i = blockIdx.x * 256 + threadIdx.x;
    if (i < n) p[i] = 0.f;
}

// ---------------- LayerNorm, split weight select (row<split -> set A) ----------------
__global__ __launch_bounds__(256) void ln_kernel(
    const float* __restrict__ X,
    const float* __restrict__ gA, const float* __restrict__ bA,
    const float* __restrict__ gB, const float* __restrict__ bB,
    int split, float* __restrict__ Y) {
    int row = blockIdx.x;
    int d = threadIdx.x;
    const float* g = (row < split) ? gA : gB;
    const float* b = (row < split) ? bA : bB;
    __shared__ float red[256];
    float v = X[(size_t)row * 256 + d];
    red[d] = v;
    __syncthreads();
    for (int s = 128; s > 0; s >>= 1) { if (d < s) red[d] += red[d + s]; __syncthreads(); }
    float mean = red[0] * (1.0f / 256.0f);
    __syncthreads();
    float dv = v - mean;
    red[d] = dv * dv;
    __syncthreads();
    for (int s = 128; s > 0; s >>= 1) { if (d < s) red[d] += red[d + s]; __syncthreads(); }
    float var = red[0] * (1.0f / 256.0f);
    float r = 1.0f / sqrtf(var + 1e-5f);
    Y[(size_t)row * 256 + d] = dv * r * g[d] + b[d];
}

// ---------------- final LN + LIF ----------------
__global__ __launch_bounds__(256) void ln_lif_kernel(
    const float* __restrict__ X, const float* __restrict__ g, const float* __restrict__ b,
    float* __restrict__ Y) {
    int row = blockIdx.x;
    int d = threadIdx.x;
    __shared__ float red[256];
    float v = X[(size_t)row * 256 + d];
    red[d] = v;
    __syncthreads();
    for (int s = 128; s > 0; s >>= 1) { if (d < s) red[d] += red[d + s]; __syncthreads(); }
    float mean = red[0] * (1.0f / 256.0f);
    __syncthreads();
    float dv = v - mean;
    red[d] = dv * dv;
    __syncthreads();
    for (int s = 128; s > 0; s >>= 1) { if (d < s) red[d] += red[d + s]; __syncthreads(); }
    float var = red[0] * (1.0f / 256.0f);
    float r = 1.0f / sqrtf(var + 1e-5f);
    float val = dv * r * g[d] + b[d];
    Y[(size_t)row * 256 + d] = (val > 1.0f) ? 1.0f : 0.0f;
}

// ---------------- tiled f32 GEMM, 64x64, BK16, double-buffered (round-8 validated) ----------------
// Bit-exact ascending-k fmaf chain. EPI 0: store; 1: store acc+R; 2: store gelu(acc)
#define BK 16
template <int EPI>
__global__ __launch_bounds__(256) void gemm_kernel(
    const float* __restrict__ A, const float* __restrict__ W0,
    const float* __restrict__ W1, int wsplit,
    float* __restrict__ C, const float* __restrict__ R,
    int M, int N, int K, int ldA, int ldW, int ldC) {
    __shared__ float As[2][BK][64 + 4];
    __shared__ float Ws[2][BK][64];
    int bm = blockIdx.y * 64;
    int bn = blockIdx.x * 64;
    const float* W = (bm < wsplit) ? W0 : W1;
    int tid = threadIdx.x;
    int tx = tid & 15;
    int ty = tid >> 4;
    int ar = tid >> 2;            // A row within tile
    int ak = (tid & 3) * 4;       // A k-offset
    int wk = tid >> 4;            // W k-row
    int wn = (tid & 15) * 4;      // W col
    int gm = bm + ar;
    bool aok = gm < M;
    const float* Aptr = A + (size_t)gm * ldA + ak;
    const float* Wptr = W + (size_t)wk * ldW + bn + wn;

    float acc[4][4] = {{0.f}};
    float4 va = aok ? *(const float4*)Aptr : make_float4(0.f, 0.f, 0.f, 0.f);
    float4 vw = *(const float4*)Wptr;
    As[0][ak + 0][ar] = va.x; As[0][ak + 1][ar] = va.y;
    As[0][ak + 2][ar] = va.z; As[0][ak + 3][ar] = va.w;
    *(float4*)&Ws[0][wk][wn] = vw;
    __syncthreads();

    int nt = K / BK;
    for (int t = 0; t < nt; ++t) {
        int cur = t & 1;
        if (t + 1 < nt) {
            va = aok ? *(const float4*)(Aptr + (t + 1) * BK)
                     : make_float4(0.f, 0.f, 0.f, 0.f);
            vw = *(const float4*)(Wptr + (size_t)(t + 1) * BK * ldW);
        }
        #pragma unroll
        for (int k = 0; k < BK; ++k) {
            float a[4], w[4];
            #pragma unroll
            for (int i = 0; i < 4; ++i) a[i] = As[cur][k][ty * 4 + i];
            #pragma unroll
            for (int j = 0; j < 4; ++j) w[j] = Ws[cur][k][tx * 4 + j];
            #pragma unroll
            for (int i = 0; i < 4; ++i)
                #pragma unroll
                for (int j = 0; j < 4; ++j)
                    acc[i][j] = fmaf(a[i], w[j], acc[i][j]);
        }
        if (t + 1 < nt) {
            int nx = cur ^ 1;
            As[nx][ak + 0][ar] = va.x; As[nx][ak + 1][ar] = va.y;
            As[nx][ak + 2][ar] = va.z; As[nx][ak + 3][ar] = va.w;
            *(float4*)&Ws[nx][wk][wn] = vw;
        }
        __syncthreads();
    }
    #pragma unroll
    for (int i = 0; i < 4; ++i) {
        int om = bm + ty * 4 + i;
        if (om >= M) continue;
        #pragma unroll
        for (int j = 0; j < 4; ++j) {
            int on = bn + tx * 4 + j;
            float v = acc[i][j];
            if (EPI == 1) v += R[(size_t)om * ldC + on];
            if (EPI == 2) v = gelu_f(v);
            C[(size_t)om * ldC + on] = v;
        }
    }
}

// ---------------- fused FF2 GEMM: C = (((R+S0)+S1)+S2)+S3, Sz over k in [z*256,z*256+256) ----------------
// Same staging as gemm_kernel; fresh accumulator per 256-k group, folded in the
// exact addff order at each boundary. K must be a multiple of 256. Bit-exact.
__global__ __launch_bounds__(256) void gemm_ff_kernel(
    const float* __restrict__ A, const float* __restrict__ W0,
    const float* __restrict__ W1, int wsplit,
    float* __restrict__ C, const float* __restrict__ R,
    int M, int K, int ldA, int ldW, int ldC) {
    __shared__ float As[2][BK][64 + 4];
    __shared__ float Ws[2][BK][64];
    int bm = blockIdx.y * 64;
    int bn = blockIdx.x * 64;
    const float* W = (bm < wsplit) ? W0 : W1;
    int tid = threadIdx.x;
    int tx = tid & 15;
    int ty = tid >> 4;
    int ar = tid >> 2;
    int ak = (tid & 3) * 4;
    int wk = tid >> 4;
    int wn = (tid & 15) * 4;
    int gm = bm + ar;
    bool aok = gm < M;
    const float* Aptr = A + (size_t)gm * ldA + ak;
    const float* Wptr = W + (size_t)wk * ldW + bn + wn;

    // ordered result v starts at residual R
    float v[4][4];
    #pragma unroll
    for (int i = 0; i < 4; ++i) {
        int om = bm + ty * 4 + i;
        #pragma unroll
        for (int j = 0; j < 4; ++j)
            v[i][j] = (om < M) ? R[(size_t)om * ldC + bn + tx * 4 + j] : 0.f;
    }
    float acc[4][4] = {{0.f}};

    float4 va = aok ? *(const float4*)Aptr : make_float4(0.f, 0.f, 0.f, 0.f);
    float4 vw = *(const float4*)Wptr;
    As[0][ak + 0][ar] = va.x; As[0][ak + 1][ar] = va.y;
    As[0][ak + 2][ar] = va.z; As[0][ak + 3][ar] = va.w;
    *(float4*)&Ws[0][wk][wn] = vw;
    __syncthreads();

    int nt = K / BK;                  // 16 tiles per 256-k group
    for (int t = 0; t < nt; ++t) {
        int cur = t & 1;
        if (t + 1 < nt) {
            va = aok ? *(const float4*)(Aptr + (t + 1) * BK)
                     : make_float4(0.f, 0.f, 0.f, 0.f);
            vw = *(const float4*)(Wptr + (size_t)(t + 1) * BK * ldW);
        }
        #pragma unroll
        for (int k = 0; k < BK; ++k) {
            float a[4], w[4];
            #pragma unroll
            for (int i = 0; i < 4; ++i) a[i] = As[cur][k][ty * 4 + i];
            #pragma unroll
            for (int j = 0; j < 4; ++j) w[j] = Ws[cur][k][tx * 4 + j];
            #pragma unroll
            for (int i = 0; i < 4; ++i)
                #pragma unroll
                for (int j = 0; j < 4; ++j)
                    acc[i][j] = fmaf(a[i], w[j], acc[i][j]);
        }
        if (t + 1 < nt) {
            int nx = cur ^ 1;
            As[nx][ak + 0][ar] = va.x; As[nx][ak + 1][ar] = va.y;
            As[nx][ak + 2][ar] = va.z; As[nx][ak + 3][ar] = va.w;
            *(float4*)&Ws[nx][wk][wn] = vw;
        }
        __syncthreads();
        if ((t & 15) == 15) {         // 256-k group boundary: ordered fold
            #pragma unroll
            for (int i = 0; i < 4; ++i)
                #pragma unroll
                for (int j = 0; j < 4; ++j) {
                    v[i][j] += acc[i][j];
                    acc[i][j] = 0.f;
                }
        }
    }
    #pragma unroll
    for (int i = 0; i < 4; ++i) {
        int om = bm + ty * 4 + i;
        if (om >= M) continue;
        #pragma unroll
        for (int j = 0; j < 4; ++j)
            C[(size_t)om * ldC + bn + tx * 4 + j] = v[i][j];
    }
}

// ---------------- attention: grid (seq, head); token base split for co-batch ----------------
__global__ __launch_bounds__(128) void attn_kernel(
    const float* __restrict__ QKV, float* __restrict__ AO,
    int N, int causal, int hs, int off2) {
    int s = blockIdx.x, h = blockIdx.y;
    int tokbase = (s < hs) ? s * N : off2 + (s - hs) * N;
    __shared__ float Ks[90][32];
    __shared__ float Vs[90][32];
    int tid = threadIdx.x;
    for (int i = tid; i < N * 32; i += 128) {
        int n = i >> 5, d = i & 31;
        size_t base = ((size_t)(tokbase + n)) * 768 + h * 32;
        Ks[n][d] = QKV[base + 256 + d];
        Vs[n][d] = QKV[base + 512 + d];
    }
    __syncthreads();
    int q = tid;
    if (q >= N) return;
    float qv[32];
    size_t qbase = ((size_t)(tokbase + q)) * 768 + h * 32;
    #pragma unroll
    for (int d = 0; d < 32; ++d) qv[d] = QKV[qbase + d];
    const float sq = 5.656854249492380195f;
    int kmax = causal ? (q + 1) : N;
    float m = -3.0e38f;
    for (int k = 0; k < kmax; ++k) {
        float sd = 0.f;
        #pragma unroll
        for (int d = 0; d < 32; ++d) sd = fmaf(qv[d], Ks[k][d], sd);
        sd /= sq;
        m = fmaxf(m, sd);
    }
    float sum = 0.f;
    float acc[32];
    #pragma unroll
    for (int d = 0; d < 32; ++d) acc[d] = 0.f;
    for (int k = 0; k < kmax; ++k) {
        float sd = 0.f;
        #pragma unroll
        for (int d = 0; d < 32; ++d) sd = fmaf(qv[d], Ks[k][d], sd);
        sd /= sq;
        float p = expf(sd - m);
        sum += p;
        #pragma unroll
        for (int d = 0; d < 32; ++d) acc[d] = fmaf(p, Vs[k][d], acc[d]);
    }
    size_t obase = ((size_t)(tokbase + q)) * 256 + h * 32;
    #pragma unroll
    for (int d = 0; d < 32; ++d) AO[obase + d] = acc[d] / sum;
}

// ---------------- suffix attention (kv cache prefix + own suffix) ----------------
__global__ __launch_bounds__(128) void suffix_attn_kernel(
    const float* __restrict__ QKV, const float* __restrict__ kv,
    float* __restrict__ AO, int g0) {
    int ls = blockIdx.x, h = blockIdx.y;
    int g = g0 + ls;
    int b = g / 90, r = g - b * 90;
    int toff = suffix_off(g) - suffix_off(g0);
    int L = 90 - r;
    __shared__ float Ks[90][32];
    __shared__ float Vs[90][32];
    int tid = threadIdx.x;
    for (int i = tid; i < 90 * 32; i += 128) {
        int p = i >> 5, d = i & 31;
        float kk, vv;
        if (p < r) {
            const float* src = kv + ((size_t)(b * 89 + p)) * 512 + h * 32 + d;
            kk = src[0]; vv = src[256];
        } else {
            size_t base = ((size_t)(toff + p - r)) * 768 + h * 32 + d;
            kk = QKV[base + 256]; vv = QKV[base + 512];
        }
        Ks[p][d] = kk; Vs[p][d] = vv;
    }
    __syncthreads();
    if (tid >= L) return;
    int jq = r + tid;
    float qv[32];
    size_t qbase = ((size_t)(toff + tid)) * 768 + h * 32;
    #pragma unroll
    for (int d = 0; d < 32; ++d) qv[d] = QKV[qbase + d];
    const float sq = 5.656854249492380195f;
    int kmax = jq + 1;
    float m = -3.0e38f;
    for (int k = 0; k < kmax; ++k) {
        float sd = 0.f;
        #pragma unroll
        for (int d = 0; d < 32; ++d) sd = fmaf(qv[d], Ks[k][d], sd);
        sd /= sq;
        m = fmaxf(m, sd);
    }
    float sum = 0.f;
    float acc[32];
    #pragma unroll
    for (int d = 0; d < 32; ++d) acc[d] = 0.f;
    for (int k = 0; k < kmax; ++k) {
        float sd = 0.f;
        #pragma unroll
        for (int d = 0; d < 32; ++d) sd = fmaf(qv[d], Ks[k][d], sd);
        sd /= sq;
        float p = expf(sd - m);
        sum += p;
        #pragma unroll
        for (int d = 0; d < 32; ++d) acc[d] = fmaf(p, Vs[k][d], acc[d]);
    }
    size_t obase = ((size_t)(toff + tid)) * 256 + h * 32;
    #pragma unroll
    for (int d = 0; d < 32; ++d) AO[obase + d] = acc[d] / sum;
}

// ---------------- last-query-only suffix attention (layer 6) ----------------
__global__ __launch_bounds__(128) void lastq_attn_kernel(
    const float* __restrict__ QKV, const float* __restrict__ kv,
    float* __restrict__ AO2, int g0) {
    int ls = blockIdx.x, h = blockIdx.y;
    int g = g0 + ls;
    int b = g / 90, r = g - b * 90;
    int toff = suffix_off(g) - suffix_off(g0);
    int L = 90 - r;
    __shared__ float Ks[90][32];
    __shared__ float Vs[90][32];
    int tid = threadIdx.x;
    for (int i = tid; i < 90 * 32; i += 128) {
        int p = i >> 5, d = i & 31;
        float kk, vv;
        if (p < r) {
            const float* src = kv + ((size_t)(b * 89 + p)) * 512 + h * 32 + d;
            kk = src[0]; vv = src[256];
        } else {
            size_t base = ((size_t)(toff + p - r)) * 768 + h * 32 + d;
            kk = QKV[base + 256]; vv = QKV[base + 512];
        }
        Ks[p][d] = kk; Vs[p][d] = vv;
    }
    __syncthreads();
    if (tid != 0) return;
    float qv[32];
    size_t qbase = ((size_t)(toff + L - 1)) * 768 + h * 32;   // query jq = 89
    #pragma unroll
    for (int d = 0; d < 32; ++d) qv[d] = QKV[qbase + d];
    const float sq = 5.656854249492380195f;
    float m = -3.0e38f;
    for (int k = 0; k < 90; ++k) {
        float sd = 0.f;
        #pragma unroll
        for (int d = 0; d < 32; ++d) sd = fmaf(qv[d], Ks[k][d], sd);
        sd /= sq;
        m = fmaxf(m, sd);
    }
    float sum = 0.f;
    float acc[32];
    #pragma unroll
    for (int d = 0; d < 32; ++d) acc[d] = 0.f;
    for (int k = 0; k < 90; ++k) {
        float sd = 0.f;
        #pragma unroll
        for (int d = 0; d < 32; ++d) sd = fmaf(qv[d], Ks[k][d], sd);
        sd /= sq;
        float p = expf(sd - m);
        sum += p;
        #pragma unroll
        for (int d = 0; d < 32; ++d) acc[d] = fmaf(p, Vs[k][d], acc[d]);
    }
    size_t obase = (size_t)ls * 256 + h * 32;
    #pragma unroll
    for (int d = 0; d < 32; ++d) AO2[obase + d] = acc[d] / sum;
}

// ---------------- masks = lif(mask_token + pos) ----------------
__global__ void masks_kernel(const float* __restrict__ mt, const float* __restrict__ pos,
                             float* __restrict__ M) {
    int i = blockIdx.x * 256 + threadIdx.x;
    if (i >= 90 * 256) return;
    int d = i & 255;
    float v = mt[d] + pos[i];
    M[i] = (v > 1.0f) ? 1.0f : 0.0f;
}

// ---------------- canonical gather (batch chunk at b0) ----------------
__global__ __launch_bounds__(256) void gather_canon_kernel(
    const float* __restrict__ student, float* __restrict__ Xc, int b0) {
    int tc = blockIdx.x;
    int d = threadIdx.x;
    int b = b0 + tc / 89, p = tc % 89;
    Xc[(size_t)tc * 256 + d] = student[((size_t)(b * 90 + p)) * 256 + d];
}

// ---------------- cache canonical K/V (batch chunk at b0) ----------------
__global__ __launch_bounds__(256) void kvcopy_kernel(
    const float* __restrict__ QKVc, float* __restrict__ kvl, int b0) {
    int tc = blockIdx.x;
    int c = threadIdx.x;
    size_t gtc = (size_t)b0 * 89 + tc;
    kvl[gtc * 512 + c]       = QKVc[(size_t)tc * 768 + 256 + c];
    kvl[gtc * 512 + 256 + c] = QKVc[(size_t)tc * 768 + 512 + c];
}

// ---------------- gather suffix tokens for seq chunk [g0, g0+c) ----------------
__global__ __launch_bounds__(256) void gather_suffix_kernel(
    const float* __restrict__ student, const float* __restrict__ masks,
    float* __restrict__ X, int g0) {
    int ls = blockIdx.x, slot = blockIdx.y;
    int d = threadIdx.x;
    int g = g0 + ls;
    int b = g / 90, r = g - b * 90;
    if (slot >= 90 - r) return;
    int j = r + slot;
    int dst = suffix_off(g) - suffix_off(g0) + slot;
    float v;
    if (j == 89) v = masks[r * 256 + d];
    else         v = student[((size_t)(b * 90 + j + 1)) * 256 + d];
    X[(size_t)dst * 256 + d] = v;
}

// ---------------- gather last-token residual rows ----------------
__global__ __launch_bounds__(256) void gather_last_kernel(
    const float* __restrict__ X, float* __restrict__ X2, int g0) {
    int ls = blockIdx.x;
    int d = threadIdx.x;
    int g = g0 + ls;
    int r = g % 90;
    int tok = suffix_off(g) - suffix_off(g0) + (89 - r);
    X2[(size_t)ls * 256 + d] = X[(size_t)tok * 256 + d];
}

// ---------------- LIF rows -> predT ----------------
__global__ __launch_bounds__(256) void lif_rows_kernel(
    const float* __restrict__ X2, float* __restrict__ predT, int g0) {
    int ls = blockIdx.x;
    int d = threadIdx.x;
    float v = X2[(size_t)ls * 256 + d];
    predT[(size_t)(g0 + ls) * 256 + d] = (v > 1.0f) ? 1.0f : 0.0f;
}

// ---------------- decode: lif(T @ W_dec + b_dec) + row mean ----------------
__global__ __launch_bounds__(256) void decode_kernel(
    const float* __restrict__ T, const float* __restrict__ Wd, const float* __restrict__ bd,
    float* __restrict__ outseq, float* __restrict__ outmean) {
    int row = blockIdx.x;
    int n = threadIdx.x;
    __shared__ float ts[256];
    __shared__ float red[256];
    ts[n] = T[(size_t)row * 256 + n];
    __syncthreads();
    float sval = 0.f;
    if (n < 240) {
        double acc = 0.0;
        for (int k = 0; k < 256; ++k)
            acc = fma((double)ts[k], (double)Wd[(size_t)k * 240 + n], acc);
        float a = (float)acc;
        a += bd[n];
        sval = (a > 1.0f) ? 1.0f : 0.0f;
        outseq[(size_t)row * 240 + n] = sval;
    }
    red[n] = sval;
    __syncthreads();
    for (int s = 128; s > 0; s >>= 1) { if (n < s) red[n] += red[n + s]; __syncthreads(); }
    if (n == 0) outmean[row] = red[0] * (1.0f / 240.0f);
}

// ---------------- target passthrough + mean ----------------
__global__ __launch_bounds__(256) void target_kernel(
    const float* __restrict__ x, float* __restrict__ outseq, float* __restrict__ outmean) {
    int row = blockIdx.x;
    int n = threadIdx.x;
    __shared__ float red[256];
    float v = 0.f;
    if (n < 240) {
        v = x[(size_t)row * 240 + n];
        outseq[(size_t)row * 240 + n] = v;
    }
    red[n] = v;
    __syncthreads();
    for (int s = 128; s > 0; s >>= 1) { if (n < s) red[n] += red[n + s]; __syncthreads(); }
    if (n == 0) outmean[row] = red[0] * (1.0f / 240.0f);
}

// ---------------- host ----------------
extern "C" void kernel_launch(void* const* d_in, const int* in_sizes, int n_in,
                              void* d_out, int out_size, void* d_ws, size_t ws_size,
                              hipStream_t stream) {
    const float* x   = (const float*)d_in[0];
    const float* We  = (const float*)d_in[1];
    const float* be  = (const float*)d_in[2];
    const float* pos = (const float*)d_in[3];
    const float* mt  = (const float*)d_in[4];
    const float* ng  = (const float*)d_in[5];
    const float* nb  = (const float*)d_in[6];
    const float* Wd  = (const float*)d_in[7];
    const float* bd  = (const float*)d_in[8];
    const float* prm[3][6];
    for (int g = 0; g < 3; ++g)
        for (int k = 0; k < 6; ++k)
            prm[g][k] = (const float*)d_in[9 + g * 6 + k];

    float* wp = (float*)d_ws;
    auto alloc = [&](size_t n) { float* q = wp; wp += n; return q; };
    float* x_emb   = alloc(720 * 256);
    float* teacher = alloc(720 * 256);
    float* student = alloc(720 * 256);
    float* predT   = alloc(720 * 256);
    float* masksb  = alloc(90 * 256);
    float* kvc     = alloc(6ull * 712 * 512);
    float* AO2 = alloc(720 * 256);
    float* X2  = alloc(720 * 256);
    float* Xn2 = alloc(720 * 256);
    float* H2  = alloc(720 * 1024);
    size_t fixed = (size_t)(wp - (float*)d_ws);

    // main buffers: per token X 256 + Xn 256 + QKV 768 + H 1024 = 2304 floats
    size_t avail = ws_size / 4;
    long tcap_l = 90;
    if (avail > fixed) {
        long t = (long)((avail - fixed) / 2304);
        if (t > tcap_l) tcap_l = t;
    }
    if (tcap_l > 32760) tcap_l = 32760;
    int TCAP = (int)tcap_l;
    float* X   = alloc((size_t)TCAP * 256);
    float* Xn  = alloc((size_t)TCAP * 256);
    float* QKV = alloc((size_t)TCAP * 768);
    float* H   = alloc((size_t)TCAP * 1024);
    bool co_batch = (TCAP >= 1488);

    float* out = (float*)d_out;
    const int NOSPLIT = 1 << 30;

    embed_kernel<<<720, 256, 0, stream>>>(x, We, be, pos, x_emb);
    masks_kernel<<<90, 256, 0, stream>>>(mt, pos, masksb);

    auto run_layer = [&](int T, int gA, int gB, int l, int split, auto&& attn_launch) {
        const float* qkvA = prm[gA][0] + (size_t)l * 256 * 768;
        const float* qkvB = prm[gB][0] + (size_t)l * 256 * 768;
        const float* woA  = prm[gA][1] + (size_t)l * 256 * 256;
        const float* woB  = prm[gB][1] + (size_t)l * 256 * 256;
        const float* l1A  = prm[gA][2] + (size_t)l * 512;
        const float* l1B  = prm[gB][2] + (size_t)l * 512;
        const float* f1A  = prm[gA][3] + (size_t)l * 256 * 1024;
        const float* f1B  = prm[gB][3] + (size_t)l * 256 * 1024;
        const float* f2A  = prm[gA][4] + (size_t)l * 1024 * 256;
        const float* f2B  = prm[gB][4] + (size_t)l * 1024 * 256;
        const float* l2A  = prm[gA][5] + (size_t)l * 512;
        const float* l2B  = prm[gB][5] + (size_t)l * 512;
        int gy = (T + 63) / 64;
        ln_kernel<<<T, 256, 0, stream>>>(X, l1A, l1A + 256, l1B, l1B + 256, split, Xn);
        gemm_kernel<0><<<dim3(12, gy), 256, 0, stream>>>(
            Xn, qkvA, qkvB, split, QKV, QKV, T, 768, 256, 256, 768, 768);
        attn_launch();
        gemm_kernel<1><<<dim3(4, gy), 256, 0, stream>>>(
            Xn, woA, woB, split, X, X, T, 256, 256, 256, 256, 256);
        ln_kernel<<<T, 256, 0, stream>>>(X, l2A, l2A + 256, l2B, l2B + 256, split, Xn);
        gemm_kernel<2><<<dim3(16, gy), 256, 0, stream>>>(
            Xn, f1A, f1B, split, H, H, T, 1024, 256, 256, 1024, 1024);
        gemm_ff_kernel<<<dim3(4, gy), 256, 0, stream>>>(
            H, f2A, f2B, split, X, X, T, 1024, 1024, 256, 256);
    };

    // ---- encoders ----
    if (co_batch) {
        copy_kernel<<<720, 256, 0, stream>>>(X, x_emb, 720 * 256);
        copy_kernel<<<720, 256, 0, stream>>>(X + 768 * 256, x_emb, 720 * 256);
        zero_kernel<<<48, 256, 0, stream>>>(X + 720 * 256, 48 * 256);
        for (int l = 0; l < 8; ++l)
            run_layer(1488, 0, 1, l, 768,
                      [&] { attn_kernel<<<dim3(16, 8), 128, 0, stream>>>(
                                QKV, Xn, 90, 0, 8, 768); });
        ln_lif_kernel<<<720, 256, 0, stream>>>(X, ng, nb, teacher);
        ln_lif_kernel<<<720, 256, 0, stream>>>(X + 768 * 256, ng, nb, student);
    } else {
        int ce = TCAP / 90; if (ce > 8) ce = 8; if (ce < 1) ce = 1;
        for (int gi = 0; gi < 2; ++gi) {
            for (int s0 = 0; s0 < 8; s0 += ce) {
                int c = (8 - s0) < ce ? (8 - s0) : ce;
                int T = c * 90;
                copy_kernel<<<(T * 256 + 255) / 256, 256, 0, stream>>>(
                    X, x_emb + (size_t)s0 * 90 * 256, T * 256);
                for (int l = 0; l < 8; ++l)
                    run_layer(T, gi, gi, l, NOSPLIT,
                              [&] { attn_kernel<<<dim3(c, 8), 128, 0, stream>>>(
                                        QKV, Xn, 90, 0, c, 0); });
                ln_lif_kernel<<<T, 256, 0, stream>>>(
                    X, ng, nb, (gi == 0 ? teacher : student) + (size_t)s0 * 90 * 256);
            }
        }
    }

    // ---- predictor phase 1: canonical prefixes, cache K/V per layer ----
    {
        int cb = TCAP / 89; if (cb > 8) cb = 8; if (cb < 1) cb = 1;
        for (int b0 = 0; b0 < 8; b0 += cb) {
            int c = (8 - b0) < cb ? (8 - b0) : cb;
            int T = c * 89;
            gather_canon_kernel<<<T, 256, 0, stream>>>(student, X, b0);
            for (int l = 0; l < 5; ++l) {
                float* kvl = kvc + (size_t)l * 712 * 512;
                run_layer(T, 2, 2, l, NOSPLIT,
                          [&] {
                              kvcopy_kernel<<<T, 256, 0, stream>>>(QKV, kvl, b0);
                              attn_kernel<<<dim3(c, 8), 128, 0, stream>>>(
                                  QKV, Xn, 89, 1, c, 0);
                          });
            }
            {   // l = 5: ln1 + qkv + kvcopy only
                const float* l1P  = prm[2][2] + 5ull * 512;
                const float* qkvP = prm[2][0] + 5ull * 256 * 768;
                float* kvl = kvc + 5ull * 712 * 512;
                int gy = (T + 63) / 64;
                ln_kernel<<<T, 256, 0, stream>>>(X, l1P, l1P + 256, l1P, l1P + 256,
                                                 NOSPLIT, Xn);
                gemm_kernel<0><<<dim3(12, gy), 256, 0, stream>>>(
                    Xn, qkvP, qkvP, NOSPLIT, QKV, QKV, T, 768, 256, 256, 768, 768);
                kvcopy_kernel<<<T, 256, 0, stream>>>(QKV, kvl, b0);
            }
        }
    }

    // ---- predictor phase 2: suffixes, chunked; layer 6 pruned to last tokens ----
    auto Toff = [](int g) { int b = g / 90, r = g - b * 90;
                            return (long)b * 4095 + 90L * r - (long)r * (r - 1) / 2; };
    int cs = TCAP / 90; if (cs < 1) cs = 1; if (cs > 720) cs = 720;
    for (int g0 = 0; g0 < 720; ) {
        int g1 = g0 + cs; if (g1 > 720) g1 = 720;
        while ((int)(Toff(g1) - Toff(g0)) > TCAP && g1 > g0 + 1) --g1;
        int c = g1 - g0;
        int Tc = (int)(Toff(g1) - Toff(g0));
        { dim3 g(c, 90);
          gather_suffix_kernel<<<g, 256, 0, stream>>>(student, masksb, X, g0); }
        for (int l = 0; l < 5; ++l) {
            float* kvl = kvc + (size_t)l * 712 * 512;
            run_layer(Tc, 2, 2, l, NOSPLIT,
                      [&] { dim3 g(c, 8);
                            suffix_attn_kernel<<<g, 128, 0, stream>>>(QKV, kvl, Xn, g0); });
        }
        {   // l = 5: full ln1+qkv (K/V needed), then last-token-only tail
            const float* qkvP = prm[2][0] + 5ull * 256 * 768;
            const float* woP  = prm[2][1] + 5ull * 256 * 256;
            const float* l1P  = prm[2][2] + 5ull * 512;
            const float* f1P  = prm[2][3] + 5ull * 256 * 1024;
            const float* f2P  = prm[2][4] + 5ull * 1024 * 256;
            const float* l2P  = prm[2][5] + 5ull * 512;
            float* kvl = kvc + 5ull * 712 * 512;
            int gy  = (Tc + 63) / 64;
            int gyc = (c + 63) / 64;
            ln_kernel<<<Tc, 256, 0, stream>>>(X, l1P, l1P + 256, l1P, l1P + 256,
                                              NOSPLIT, Xn);
            gemm_kernel<0><<<dim3(12, gy), 256, 0, stream>>>(
                Xn, qkvP, qkvP, NOSPLIT, QKV, QKV, Tc, 768, 256, 256, 768, 768);
            { dim3 g(c, 8);
              lastq_attn_kernel<<<g, 128, 0, stream>>>(QKV, kvl, AO2, g0); }
            gather_last_kernel<<<c, 256, 0, stream>>>(X, X2, g0);
            gemm_kernel<1><<<dim3(4, gyc), 256, 0, stream>>>(
                AO2, woP, woP, NOSPLIT, X2, X2, c, 256, 256, 256, 256, 256);
            ln_kernel<<<c, 256, 0, stream>>>(X2, l2P, l2P + 256, l2P, l2P + 256,
                                             NOSPLIT, Xn2);
            gemm_kernel<2><<<dim3(16, gyc), 256, 0, stream>>>(
                Xn2, f1P, f1P, NOSPLIT, H2, H2, c, 1024, 256, 256, 1024, 1024);
            gemm_ff_kernel<<<dim3(4, gyc), 256, 0, stream>>>(
                H2, f2P, f2P, NOSPLIT, X2, X2, c, 1024, 1024, 256, 256);
            lif_rows_kernel<<<c, 256, 0, stream>>>(X2, predT, g0);
        }
        g0 = g1;
    }

    decode_kernel<<<720, 256, 0, stream>>>(predT, Wd, bd, out + 0, out + 518400);
    decode_kernel<<<720, 256, 0, stream>>>(teacher, Wd, bd, out + 172800, out + 519120);
    target_kernel<<<720, 256, 0, stream>>>(x, out + 345600, out + 519840);
}

// Round 11
// 9180.628 us; speedup vs baseline: 1.4132x; 1.0772x over previous
//
#include <hip/hip_runtime.h>
#include <math.h>

// NOTE: binary spike outputs require BIT-EXACT reproduction of the validated
// reduction orders (rounds 2/5/6/8). Base = round-8 kernel (9.43 ms, best
// measured). New this round (attention only):
//  - suffix_attn v2: sd cached in LDS during pass 1 (identical values), pass 2
//    reads cache instead of recomputing the serial dot; queries split across
//    blockIdx.z in [0,45)/[45,90) for load balance. max/sum/acc chains are in
//    the identical order => bit-exact.
//  - lastq_attn v2: 32 lanes run the identical redundant pass-1 chain (sd
//    cached), pass 2 does redundant exp/sum + per-lane acc[d]. Bit-exact.

// ---------------- device helpers ----------------
__device__ __forceinline__ float gelu_f(float x) {
    const float c = 0.7978845608028654f; // sqrt(2/pi)
    float x3 = x * x * x;
    float inner = c * (x + 0.044715f * x3);
    return 0.5f * x * (1.0f + tanhf(inner));
}

__device__ __forceinline__ int suffix_off(int g) {
    int b = g / 90, r = g - b * 90;
    return b * 4095 + 90 * r - ((r * (r - 1)) >> 1);
}

// ---------------- embed: x @ W_embed + b + pos, LIF ----------------
__global__ __launch_bounds__(256) void embed_kernel(
    const float* __restrict__ x, const float* __restrict__ We,
    const float* __restrict__ be, const float* __restrict__ pos,
    float* __restrict__ xemb) {
    int tok = blockIdx.x;
    int d = threadIdx.x;
    __shared__ float xs[240];
    if (d < 240) xs[d] = x[(size_t)tok * 240 + d];
    __syncthreads();
    int r = tok % 90;
    double acc = 0.0;
    for (int s = 0; s < 240; ++s)
        acc = fma((double)xs[s], (double)We[(size_t)s * 256 + d], acc);
    float a = (float)acc + be[d] + pos[r * 256 + d];
    xemb[(size_t)tok * 256 + d] = (a > 1.0f) ? 1.0f : 0.0f;
}

// ---------------- simple copy / zero ----------------
__global__ void copy_kernel(float* __restrict__ dst, const float* __restrict__ src, int n) {
    int i = blockIdx.x * 256 + threadIdx.x;
    if (i < n) dst[i] = src[i];
}
__global__ void zero_kernel(float* __restrict__ p, int n) {
    int i = blockIdx.x * 256 + threadIdx.x;
    if (i < n) p[i] = 0.f;
}

// ---------------- LayerNorm, split weight select (row<split -> set A) ----------------
__global__ __launch_bounds__(256) void ln_kernel(
    const float* __restrict__ X,
    const float* __restrict__ gA, const float* __restrict__ bA,
    const float* __restrict__ gB, const float* __restrict__ bB,
    int split, float* __restrict__ Y) {
    int row = blockIdx.x;
    int d = threadIdx.x;
    const float* g = (row < split) ? gA : gB;
    const float* b = (row < split) ? bA : bB;
    __shared__ float red[256];
    float v = X[(size_t)row * 256 + d];
    red[d] = v;
    __syncthreads();
    for (int s = 128; s > 0; s >>= 1) { if (d < s) red[d] += red[d + s]; __syncthreads(); }
    float mean = red[0] * (1.0f / 256.0f);
    __syncthreads();
    float dv = v - mean;
    red[d] = dv * dv;
    __syncthreads();
    for (int s = 128; s > 0; s >>= 1) { if (d < s) red[d] += red[d + s]; __syncthreads(); }
    float var = red[0] * (1.0f / 256.0f);
    float r = 1.0f / sqrtf(var + 1e-5f);
    Y[(size_t)row * 256 + d] = dv * r * g[d] + b[d];
}

// ---------------- final LN + LIF ----------------
__global__ __launch_bounds__(256) void ln_lif_kernel(
    const float* __restrict__ X, const float* __restrict__ g, const float* __restrict__ b,
    float* __restrict__ Y) {
    int row = blockIdx.x;
    int d = threadIdx.x;
    __shared__ float red[256];
    float v = X[(size_t)row * 256 + d];
    red[d] = v;
    __syncthreads();
    for (int s = 128; s > 0; s >>= 1) { if (d < s) red[d] += red[d + s]; __syncthreads(); }
    float mean = red[0] * (1.0f / 256.0f);
    __syncthreads();
    float dv = v - mean;
    red[d] = dv * dv;
    __syncthreads();
    for (int s = 128; s > 0; s >>= 1) { if (d < s) red[d] += red[d + s]; __syncthreads(); }
    float var = red[0] * (1.0f / 256.0f);
    float r = 1.0f / sqrtf(var + 1e-5f);
    float val = dv * r * g[d] + b[d];
    Y[(size_t)row * 256 + d] = (val > 1.0f) ? 1.0f : 0.0f;
}

// ---------------- tiled f32 GEMM, 64x64, BK16, double-buffered (round-8 validated) ----------------
// Bit-exact ascending-k fmaf chain. EPI 0: store; 1: store acc+R; 2: store gelu(acc)
#define BK 16
template <int EPI>
__global__ __launch_bounds__(256) void gemm_kernel(
    const float* __restrict__ A, const float* __restrict__ W0,
    const float* __restrict__ W1, int wsplit,
    float* __restrict__ C, const float* __restrict__ R,
    int M, int N, int K, int ldA, int ldW, int ldC,
    int zA, int zW, long zC) {
    __shared__ float As[2][BK][64 + 4];
    __shared__ float Ws[2][BK][64];
    int bm = blockIdx.y * 64;
    int bn = blockIdx.x * 64;
    int z = blockIdx.z;
    A += (size_t)z * zA;
    const float* W = ((bm < wsplit) ? W0 : W1) + (size_t)z * zW;
    C += (size_t)z * zC;
    const float* Rp = R + (size_t)z * zC;
    int tid = threadIdx.x;
    int tx = tid & 15;
    int ty = tid >> 4;
    int ar = tid >> 2;            // A row within tile
    int ak = (tid & 3) * 4;       // A k-offset
    int wk = tid >> 4;            // W k-row
    int wn = (tid & 15) * 4;      // W col
    int gm = bm + ar;
    bool aok = gm < M;
    const float* Aptr = A + (size_t)gm * ldA + ak;
    const float* Wptr = W + (size_t)wk * ldW + bn + wn;

    float acc[4][4] = {{0.f}};
    float4 va = aok ? *(const float4*)Aptr : make_float4(0.f, 0.f, 0.f, 0.f);
    float4 vw = *(const float4*)Wptr;
    As[0][ak + 0][ar] = va.x; As[0][ak + 1][ar] = va.y;
    As[0][ak + 2][ar] = va.z; As[0][ak + 3][ar] = va.w;
    *(float4*)&Ws[0][wk][wn] = vw;
    __syncthreads();

    int nt = K / BK;
    for (int t = 0; t < nt; ++t) {
        int cur = t & 1;
        if (t + 1 < nt) {
            va = aok ? *(const float4*)(Aptr + (t + 1) * BK)
                     : make_float4(0.f, 0.f, 0.f, 0.f);
            vw = *(const float4*)(Wptr + (size_t)(t + 1) * BK * ldW);
        }
        #pragma unroll
        for (int k = 0; k < BK; ++k) {
            float a[4], w[4];
            #pragma unroll
            for (int i = 0; i < 4; ++i) a[i] = As[cur][k][ty * 4 + i];
            #pragma unroll
            for (int j = 0; j < 4; ++j) w[j] = Ws[cur][k][tx * 4 + j];
            #pragma unroll
            for (int i = 0; i < 4; ++i)
                #pragma unroll
                for (int j = 0; j < 4; ++j)
                    acc[i][j] = fmaf(a[i], w[j], acc[i][j]);
        }
        if (t + 1 < nt) {
            int nx = cur ^ 1;
            As[nx][ak + 0][ar] = va.x; As[nx][ak + 1][ar] = va.y;
            As[nx][ak + 2][ar] = va.z; As[nx][ak + 3][ar] = va.w;
            *(float4*)&Ws[nx][wk][wn] = vw;
        }
        __syncthreads();
    }
    #pragma unroll
    for (int i = 0; i < 4; ++i) {
        int om = bm + ty * 4 + i;
        if (om >= M) continue;
        #pragma unroll
        for (int j = 0; j < 4; ++j) {
            int on = bn + tx * 4 + j;
            float v = acc[i][j];
            if (EPI == 1) v += Rp[(size_t)om * ldC + on];
            if (EPI == 2) v = gelu_f(v);
            C[(size_t)om * ldC + on] = v;
        }
    }
}

// ---------------- ordered FF accumulate: X = (((X+S0)+S1)+S2)+S3 ----------------
__global__ void addff_kernel(float4* __restrict__ X, const float4* __restrict__ S,
                             long zstr4, int n4) {
    int i = blockIdx.x * 256 + threadIdx.x;
    if (i >= n4) return;
    float4 x = X[i];
    float4 s0 = S[i], s1 = S[i + zstr4], s2 = S[i + 2 * zstr4], s3 = S[i + 3 * zstr4];
    x.x = (((x.x + s0.x) + s1.x) + s2.x) + s3.x;
    x.y = (((x.y + s0.y) + s1.y) + s2.y) + s3.y;
    x.z = (((x.z + s0.z) + s1.z) + s2.z) + s3.z;
    x.w = (((x.w + s0.w) + s1.w) + s2.w) + s3.w;
    X[i] = x;
}

// ---------------- attention: grid (seq, head); token base split for co-batch ----------------
__global__ __launch_bounds__(128) void attn_kernel(
    const float* __restrict__ QKV, float* __restrict__ AO,
    int N, int causal, int hs, int off2) {
    int s = blockIdx.x, h = blockIdx.y;
    int tokbase = (s < hs) ? s * N : off2 + (s - hs) * N;
    __shared__ float Ks[90][32];
    __shared__ float Vs[90][32];
    int tid = threadIdx.x;
    for (int i = tid; i < N * 32; i += 128) {
        int n = i >> 5, d = i & 31;
        size_t base = ((size_t)(tokbase + n)) * 768 + h * 32;
        Ks[n][d] = QKV[base + 256 + d];
        Vs[n][d] = QKV[base + 512 + d];
    }
    __syncthreads();
    int q = tid;
    if (q >= N) return;
    float qv[32];
    size_t qbase = ((size_t)(tokbase + q)) * 768 + h * 32;
    #pragma unroll
    for (int d = 0; d < 32; ++d) qv[d] = QKV[qbase + d];
    const float sq = 5.656854249492380195f;
    int kmax = causal ? (q + 1) : N;
    float m = -3.0e38f;
    for (int k = 0; k < kmax; ++k) {
        float sd = 0.f;
        #pragma unroll
        for (int d = 0; d < 32; ++d) sd = fmaf(qv[d], Ks[k][d], sd);
        sd /= sq;
        m = fmaxf(m, sd);
    }
    float sum = 0.f;
    float acc[32];
    #pragma unroll
    for (int d = 0; d < 32; ++d) acc[d] = 0.f;
    for (int k = 0; k < kmax; ++k) {
        float sd = 0.f;
        #pragma unroll
        for (int d = 0; d < 32; ++d) sd = fmaf(qv[d], Ks[k][d], sd);
        sd /= sq;
        float p = expf(sd - m);
        sum += p;
        #pragma unroll
        for (int d = 0; d < 32; ++d) acc[d] = fmaf(p, Vs[k][d], acc[d]);
    }
    size_t obase = ((size_t)(tokbase + q)) * 256 + h * 32;
    #pragma unroll
    for (int d = 0; d < 32; ++d) AO[obase + d] = acc[d] / sum;
}

// ---------------- suffix attention v2: sd-cache + query-split ----------------
// grid (c, 8, 2); blockIdx.z selects suffix-slot range [0,45) / [45,90).
// Pass 1 computes the identical serial sd chain, caching sd in LDS; pass 2
// reads the cache (identical values) -> exp/sum/acc in the identical order.
__global__ __launch_bounds__(128) void suffix_attn_kernel(
    const float* __restrict__ QKV, const float* __restrict__ kv,
    float* __restrict__ AO, int g0) {
    int ls = blockIdx.x, h = blockIdx.y, q0 = blockIdx.z * 45;
    int g = g0 + ls;
    int b = g / 90, r = g - b * 90;
    int toff = suffix_off(g) - suffix_off(g0);
    int L = 90 - r;
    if (q0 >= L) return;                       // block-uniform early-out
    __shared__ float Ks[90][32];
    __shared__ float Vs[90][32];
    __shared__ float Ssd[45][91];
    int tid = threadIdx.x;
    int kstage = r + q0 + 45; if (kstage > 90) kstage = 90;
    for (int i = tid; i < kstage * 32; i += 128) {
        int p = i >> 5, d = i & 31;
        float kk, vv;
        if (p < r) {
            const float* src = kv + ((size_t)(b * 89 + p)) * 512 + h * 32 + d;
            kk = src[0]; vv = src[256];
        } else {
            size_t base = ((size_t)(toff + p - r)) * 768 + h * 32 + d;
            kk = QKV[base + 256]; vv = QKV[base + 512];
        }
        Ks[p][d] = kk; Vs[p][d] = vv;
    }
    __syncthreads();
    int qi = tid;                              // 0..44 active
    int tq = q0 + qi;                          // suffix slot
    if (qi >= 45 || tq >= L) return;
    int jq = r + tq;                           // global query position
    float qv[32];
    size_t qbase = ((size_t)(toff + tq)) * 768 + h * 32;
    #pragma unroll
    for (int d = 0; d < 32; ++d) qv[d] = QKV[qbase + d];
    const float sq = 5.656854249492380195f;
    int kmax = jq + 1;
    float* srow = Ssd[qi];
    float m = -3.0e38f;
    for (int k = 0; k < kmax; ++k) {
        float sd = 0.f;
        #pragma unroll
        for (int d = 0; d < 32; ++d) sd = fmaf(qv[d], Ks[k][d], sd);
        sd /= sq;
        srow[k] = sd;
        m = fmaxf(m, sd);
    }
    float sum = 0.f;
    float acc[32];
    #pragma unroll
    for (int d = 0; d < 32; ++d) acc[d] = 0.f;
    for (int k = 0; k < kmax; ++k) {
        float p = expf(srow[k] - m);
        sum += p;
        #pragma unroll
        for (int d = 0; d < 32; ++d) acc[d] = fmaf(p, Vs[k][d], acc[d]);
    }
    size_t obase = ((size_t)(toff + tq)) * 256 + h * 32;
    #pragma unroll
    for (int d = 0; d < 32; ++d) AO[obase + d] = acc[d] / sum;
}

// ---------------- last-query-only suffix attention v2 (layer 6) ----------------
// 32 lanes run the identical redundant pass-1 chain (sd cached in LDS); pass 2
// is redundant exp/sum (identical chains) + one fmaf per lane for acc[d].
__global__ __launch_bounds__(128) void lastq_attn_kernel(
    const float* __restrict__ QKV, const float* __restrict__ kv,
    float* __restrict__ AO2, int g0) {
    int ls = blockIdx.x, h = blockIdx.y;
    int g = g0 + ls;
    int b = g / 90, r = g - b * 90;
    int toff = suffix_off(g) - suffix_off(g0);
    int L = 90 - r;
    __shared__ float Ks[90][32];
    __shared__ float Vs[90][32];
    __shared__ float sdbuf[90];
    int tid = threadIdx.x;
    for (int i = tid; i < 90 * 32; i += 128) {
        int p = i >> 5, d = i & 31;
        float kk, vv;
        if (p < r) {
            const float* src = kv + ((size_t)(b * 89 + p)) * 512 + h * 32 + d;
            kk = src[0]; vv = src[256];
        } else {
            size_t base = ((size_t)(toff + p - r)) * 768 + h * 32 + d;
            kk = QKV[base + 256]; vv = QKV[base + 512];
        }
        Ks[p][d] = kk; Vs[p][d] = vv;
    }
    __syncthreads();
    if (tid >= 32) return;
    int d = tid;
    float qv[32];
    size_t qbase = ((size_t)(toff + L - 1)) * 768 + h * 32;   // query jq = 89
    #pragma unroll
    for (int i = 0; i < 32; ++i) qv[i] = QKV[qbase + i];
    const float sq = 5.656854249492380195f;
    float m = -3.0e38f;
    for (int k = 0; k < 90; ++k) {
        float sd = 0.f;
        #pragma unroll
        for (int i = 0; i < 32; ++i) sd = fmaf(qv[i], Ks[k][i], sd);
        sd /= sq;
        sdbuf[k] = sd;                 // all lanes write identical value
        m = fmaxf(m, sd);
    }
    float sum = 0.f;
    float acc = 0.f;
    for (int k = 0; k < 90; ++k) {
        float p = expf(sdbuf[k] - m);  // identical redundant chain per lane
        sum += p;
        acc = fmaf(p, Vs[k][d], acc);
    }
    AO2[(size_t)ls * 256 + h * 32 + d] = acc / sum;
}

// ---------------- masks = lif(mask_token + pos) ----------------
__global__ void masks_kernel(const float* __restrict__ mt, const float* __restrict__ pos,
                             float* __restrict__ M) {
    int i = blockIdx.x * 256 + threadIdx.x;
    if (i >= 90 * 256) return;
    int d = i & 255;
    float v = mt[d] + pos[i];
    M[i] = (v > 1.0f) ? 1.0f : 0.0f;
}

// ---------------- canonical gather (batch chunk at b0) ----------------
__global__ __launch_bounds__(256) void gather_canon_kernel(
    const float* __restrict__ student, float* __restrict__ Xc, int b0) {
    int tc = blockIdx.x;
    int d = threadIdx.x;
    int b = b0 + tc / 89, p = tc % 89;
    Xc[(size_t)tc * 256 + d] = student[((size_t)(b * 90 + p)) * 256 + d];
}

// ---------------- cache canonical K/V (batch chunk at b0) ----------------
__global__ __launch_bounds__(256) void kvcopy_kernel(
    const float* __restrict__ QKVc, float* __restrict__ kvl, int b0) {
    int tc = blockIdx.x;
    int c = threadIdx.x;
    size_t gtc = (size_t)b0 * 89 + tc;
    kvl[gtc * 512 + c]       = QKVc[(size_t)tc * 768 + 256 + c];
    kvl[gtc * 512 + 256 + c] = QKVc[(size_t)tc * 768 + 512 + c];
}

// ---------------- gather suffix tokens for seq chunk [g0, g0+c) ----------------
__global__ __launch_bounds__(256) void gather_suffix_kernel(
    const float* __restrict__ student, const float* __restrict__ masks,
    float* __restrict__ X, int g0) {
    int ls = blockIdx.x, slot = blockIdx.y;
    int d = threadIdx.x;
    int g = g0 + ls;
    int b = g / 90, r = g - b * 90;
    if (slot >= 90 - r) return;
    int j = r + slot;
    int dst = suffix_off(g) - suffix_off(g0) + slot;
    float v;
    if (j == 89) v = masks[r * 256 + d];
    else         v = student[((size_t)(b * 90 + j + 1)) * 256 + d];
    X[(size_t)dst * 256 + d] = v;
}

// ---------------- gather last-token residual rows ----------------
__global__ __launch_bounds__(256) void gather_last_kernel(
    const float* __restrict__ X, float* __restrict__ X2, int g0) {
    int ls = blockIdx.x;
    int d = threadIdx.x;
    int g = g0 + ls;
    int r = g % 90;
    int tok = suffix_off(g) - suffix_off(g0) + (89 - r);
    X2[(size_t)ls * 256 + d] = X[(size_t)tok * 256 + d];
}

// ---------------- LIF rows -> predT ----------------
__global__ __launch_bounds__(256) void lif_rows_kernel(
    const float* __restrict__ X2, float* __restrict__ predT, int g0) {
    int ls = blockIdx.x;
    int d = threadIdx.x;
    float v = X2[(size_t)ls * 256 + d];
    predT[(size_t)(g0 + ls) * 256 + d] = (v > 1.0f) ? 1.0f : 0.0f;
}

// ---------------- decode: lif(T @ W_dec + b_dec) + row mean ----------------
__global__ __launch_bounds__(256) void decode_kernel(
    const float* __restrict__ T, const float* __restrict__ Wd, const float* __restrict__ bd,
    float* __restrict__ outseq, float* __restrict__ outmean) {
    int row = blockIdx.x;
    int n = threadIdx.x;
    __shared__ float ts[256];
    __shared__ float red[256];
    ts[n] = T[(size_t)row * 256 + n];
    __syncthreads();
    float sval = 0.f;
    if (n < 240) {
        double acc = 0.0;
        for (int k = 0; k < 256; ++k)
            acc = fma((double)ts[k], (double)Wd[(size_t)k * 240 + n], acc);
        float a = (float)acc;
        a += bd[n];
        sval = (a > 1.0f) ? 1.0f : 0.0f;
        outseq[(size_t)row * 240 + n] = sval;
    }
    red[n] = sval;
    __syncthreads();
    for (int s = 128; s > 0; s >>= 1) { if (n < s) red[n] += red[n + s]; __syncthreads(); }
    if (n == 0) outmean[row] = red[0] * (1.0f / 240.0f);
}

// ---------------- target passthrough + mean ----------------
__global__ __launch_bounds__(256) void target_kernel(
    const float* __restrict__ x, float* __restrict__ outseq, float* __restrict__ outmean) {
    int row = blockIdx.x;
    int n = threadIdx.x;
    __shared__ float red[256];
    float v = 0.f;
    if (n < 240) {
        v = x[(size_t)row * 240 + n];
        outseq[(size_t)row * 240 + n] = v;
    }
    red[n] = v;
    __syncthreads();
    for (int s = 128; s > 0; s >>= 1) { if (n < s) red[n] += red[n + s]; __syncthreads(); }
    if (n == 0) outmean[row] = red[0] * (1.0f / 240.0f);
}

// ---------------- host ----------------
extern "C" void kernel_launch(void* const* d_in, const int* in_sizes, int n_in,
                              void* d_out, int out_size, void* d_ws, size_t ws_size,
                              hipStream_t stream) {
    const float* x   = (const float*)d_in[0];
    const float* We  = (const float*)d_in[1];
    const float* be  = (const float*)d_in[2];
    const float* pos = (const float*)d_in[3];
    const float* mt  = (const float*)d_in[4];
    const float* ng  = (const float*)d_in[5];
    const float* nb  = (const float*)d_in[6];
    const float* Wd  = (const float*)d_in[7];
    const float* bd  = (const float*)d_in[8];
    const float* prm[3][6];
    for (int g = 0; g < 3; ++g)
        for (int k = 0; k < 6; ++k)
            prm[g][k] = (const float*)d_in[9 + g * 6 + k];

    float* wp = (float*)d_ws;
    auto alloc = [&](size_t n) { float* q = wp; wp += n; return q; };
    float* x_emb   = alloc(720 * 256);
    float* teacher = alloc(720 * 256);
    float* student = alloc(720 * 256);
    float* predT   = alloc(720 * 256);
    float* masksb  = alloc(90 * 256);
    float* kvc     = alloc(6ull * 712 * 512);
    // layer-6 compact buffers (max 720 rows)
    float* AO2 = alloc(720 * 256);
    float* X2  = alloc(720 * 256);
    float* Xn2 = alloc(720 * 256);
    float* H2  = alloc(720 * 1024);
    float* S2  = alloc(4ull * 720 * 256);
    long  zS2  = 720 * 256;
    size_t fixed = (size_t)(wp - (float*)d_ws);

    // main buffers: per token X 256 + Xn 256 + QKV 768 + H 1024 + S 4*256 = 3328
    size_t avail = ws_size / 4;
    long tcap_l = 90;
    if (avail > fixed) {
        long t = (long)((avail - fixed) / 3328);
        if (t > tcap_l) tcap_l = t;
    }
    if (tcap_l > 32760) tcap_l = 32760;
    int TCAP = (int)tcap_l;
    float* X   = alloc((size_t)TCAP * 256);
    float* Xn  = alloc((size_t)TCAP * 256);
    float* QKV = alloc((size_t)TCAP * 768);
    float* H   = alloc((size_t)TCAP * 1024);
    float* S   = alloc(4ull * TCAP * 256);
    long  zS   = (long)TCAP * 256;
    bool co_batch = (TCAP >= 1488);

    float* out = (float*)d_out;
    const int NOSPLIT = 1 << 30;

    embed_kernel<<<720, 256, 0, stream>>>(x, We, be, pos, x_emb);
    masks_kernel<<<90, 256, 0, stream>>>(mt, pos, masksb);

    auto run_layer = [&](int T, int gA, int gB, int l, int split, auto&& attn_launch) {
        const float* qkvA = prm[gA][0] + (size_t)l * 256 * 768;
        const float* qkvB = prm[gB][0] + (size_t)l * 256 * 768;
        const float* woA  = prm[gA][1] + (size_t)l * 256 * 256;
        const float* woB  = prm[gB][1] + (size_t)l * 256 * 256;
        const float* l1A  = prm[gA][2] + (size_t)l * 512;
        const float* l1B  = prm[gB][2] + (size_t)l * 512;
        const float* f1A  = prm[gA][3] + (size_t)l * 256 * 1024;
        const float* f1B  = prm[gB][3] + (size_t)l * 256 * 1024;
        const float* f2A  = prm[gA][4] + (size_t)l * 1024 * 256;
        const float* f2B  = prm[gB][4] + (size_t)l * 1024 * 256;
        const float* l2A  = prm[gA][5] + (size_t)l * 512;
        const float* l2B  = prm[gB][5] + (size_t)l * 512;
        int gy = (T + 63) / 64;
        ln_kernel<<<T, 256, 0, stream>>>(X, l1A, l1A + 256, l1B, l1B + 256, split, Xn);
        gemm_kernel<0><<<dim3(12, gy, 1), 256, 0, stream>>>(
            Xn, qkvA, qkvB, split, QKV, QKV, T, 768, 256, 256, 768, 768, 0, 0, 0);
        attn_launch();
        gemm_kernel<1><<<dim3(4, gy, 1), 256, 0, stream>>>(
            Xn, woA, woB, split, X, X, T, 256, 256, 256, 256, 256, 0, 0, 0);
        ln_kernel<<<T, 256, 0, stream>>>(X, l2A, l2A + 256, l2B, l2B + 256, split, Xn);
        gemm_kernel<2><<<dim3(16, gy, 1), 256, 0, stream>>>(
            Xn, f1A, f1B, split, H, H, T, 1024, 256, 256, 1024, 1024, 0, 0, 0);
        gemm_kernel<0><<<dim3(4, gy, 4), 256, 0, stream>>>(
            H, f2A, f2B, split, S, S, T, 256, 256, 1024, 256, 256, 256, 65536, zS);
        addff_kernel<<<(T * 64 + 255) / 256, 256, 0, stream>>>(
            (float4*)X, (const float4*)S, zS / 4, T * 64);
    };

    // ---- encoders ----
    if (co_batch) {
        copy_kernel<<<720, 256, 0, stream>>>(X, x_emb, 720 * 256);
        copy_kernel<<<720, 256, 0, stream>>>(X + 768 * 256, x_emb, 720 * 256);
        zero_kernel<<<48, 256, 0, stream>>>(X + 720 * 256, 48 * 256);
        for (int l = 0; l < 8; ++l)
            run_layer(1488, 0, 1, l, 768,
                      [&] { attn_kernel<<<dim3(16, 8), 128, 0, stream>>>(
                                QKV, Xn, 90, 0, 8, 768); });
        ln_lif_kernel<<<720, 256, 0, stream>>>(X, ng, nb, teacher);
        ln_lif_kernel<<<720, 256, 0, stream>>>(X + 768 * 256, ng, nb, student);
    } else {
        int ce = TCAP / 90; if (ce > 8) ce = 8; if (ce < 1) ce = 1;
        for (int gi = 0; gi < 2; ++gi) {
            for (int s0 = 0; s0 < 8; s0 += ce) {
                int c = (8 - s0) < ce ? (8 - s0) : ce;
                int T = c * 90;
                copy_kernel<<<(T * 256 + 255) / 256, 256, 0, stream>>>(
                    X, x_emb + (size_t)s0 * 90 * 256, T * 256);
                for (int l = 0; l < 8; ++l)
                    run_layer(T, gi, gi, l, NOSPLIT,
                              [&] { attn_kernel<<<dim3(c, 8), 128, 0, stream>>>(
                                        QKV, Xn, 90, 0, c, 0); });
                ln_lif_kernel<<<T, 256, 0, stream>>>(
                    X, ng, nb, (gi == 0 ? teacher : student) + (size_t)s0 * 90 * 256);
            }
        }
    }

    // ---- predictor phase 1: canonical prefixes, cache K/V per layer ----
    // Layer 6 (l=5) of the canonical pass only needs K/V -> stop after kvcopy.
    {
        int cb = TCAP / 89; if (cb > 8) cb = 8; if (cb < 1) cb = 1;
        for (int b0 = 0; b0 < 8; b0 += cb) {
            int c = (8 - b0) < cb ? (8 - b0) : cb;
            int T = c * 89;
            gather_canon_kernel<<<T, 256, 0, stream>>>(student, X, b0);
            for (int l = 0; l < 5; ++l) {
                float* kvl = kvc + (size_t)l * 712 * 512;
                run_layer(T, 2, 2, l, NOSPLIT,
                          [&] {
                              kvcopy_kernel<<<T, 256, 0, stream>>>(QKV, kvl, b0);
                              attn_kernel<<<dim3(c, 8), 128, 0, stream>>>(
                                  QKV, Xn, 89, 1, c, 0);
                          });
            }
            {   // l = 5: ln1 + qkv + kvcopy only
                const float* l1P  = prm[2][2] + 5ull * 512;
                const float* qkvP = prm[2][0] + 5ull * 256 * 768;
                float* kvl = kvc + 5ull * 712 * 512;
                int gy = (T + 63) / 64;
                ln_kernel<<<T, 256, 0, stream>>>(X, l1P, l1P + 256, l1P, l1P + 256,
                                                 NOSPLIT, Xn);
                gemm_kernel<0><<<dim3(12, gy, 1), 256, 0, stream>>>(
                    Xn, qkvP, qkvP, NOSPLIT, QKV, QKV, T, 768, 256, 256, 768, 768, 0, 0, 0);
                kvcopy_kernel<<<T, 256, 0, stream>>>(QKV, kvl, b0);
            }
        }
    }

    // ---- predictor phase 2: suffixes, chunked; layer 6 pruned to last tokens ----
    auto Toff = [](int g) { int b = g / 90, r = g - b * 90;
                            return (long)b * 4095 + 90L * r - (long)r * (r - 1) / 2; };
    int cs = TCAP / 90; if (cs < 1) cs = 1; if (cs > 720) cs = 720;
    for (int g0 = 0; g0 < 720; ) {
        int g1 = g0 + cs; if (g1 > 720) g1 = 720;
        while ((int)(Toff(g1) - Toff(g0)) > TCAP && g1 > g0 + 1) --g1;
        int c = g1 - g0;
        int Tc = (int)(Toff(g1) - Toff(g0));
        { dim3 g(c, 90);
          gather_suffix_kernel<<<g, 256, 0, stream>>>(student, masksb, X, g0); }
        for (int l = 0; l < 5; ++l) {
            float* kvl = kvc + (size_t)l * 712 * 512;
            run_layer(Tc, 2, 2, l, NOSPLIT,
                      [&] { dim3 g(c, 8, 2);
                            suffix_attn_kernel<<<g, 128, 0, stream>>>(QKV, kvl, Xn, g0); });
        }
        {   // l = 5: full ln1+qkv (K/V needed), then last-token-only tail
            const float* qkvP = prm[2][0] + 5ull * 256 * 768;
            const float* woP  = prm[2][1] + 5ull * 256 * 256;
            const float* l1P  = prm[2][2] + 5ull * 512;
            const float* f1P  = prm[2][3] + 5ull * 256 * 1024;
            const float* f2P  = prm[2][4] + 5ull * 1024 * 256;
            const float* l2P  = prm[2][5] + 5ull * 512;
            float* kvl = kvc + 5ull * 712 * 512;
            int gy  = (Tc + 63) / 64;
            int gyc = (c + 63) / 64;
            ln_kernel<<<Tc, 256, 0, stream>>>(X, l1P, l1P + 256, l1P, l1P + 256,
                                              NOSPLIT, Xn);
            gemm_kernel<0><<<dim3(12, gy, 1), 256, 0, stream>>>(
                Xn, qkvP, qkvP, NOSPLIT, QKV, QKV, Tc, 768, 256, 256, 768, 768, 0, 0, 0);
            { dim3 g(c, 8);
              lastq_attn_kernel<<<g, 128, 0, stream>>>(QKV, kvl, AO2, g0); }
            gather_last_kernel<<<c, 256, 0, stream>>>(X, X2, g0);
            gemm_kernel<1><<<dim3(4, gyc, 1), 256, 0, stream>>>(
                AO2, woP, woP, NOSPLIT, X2, X2, c, 256, 256, 256, 256, 256, 0, 0, 0);
            ln_kernel<<<c, 256, 0, stream>>>(X2, l2P, l2P + 256, l2P, l2P + 256,
                                             NOSPLIT, Xn2);
            gemm_kernel<2><<<dim3(16, gyc, 1), 256, 0, stream>>>(
                Xn2, f1P, f1P, NOSPLIT, H2, H2, c, 1024, 256, 256, 1024, 1024, 0, 0, 0);
            gemm_kernel<0><<<dim3(4, gyc, 4), 256, 0, stream>>>(
                H2, f2P, f2P, NOSPLIT, S2, S2, c, 256, 256, 1024, 256, 256, 256, 65536, zS2);
            addff_kernel<<<(c * 64 + 255) / 256, 256, 0, stream>>>(
                (float4*)X2, (const float4*)S2, zS2 / 4, c * 64);
            lif_rows_kernel<<<c, 256, 0, stream>>>(X2, predT, g0);
        }
        g0 = g1;
    }

    decode_kernel<<<720, 256, 0, stream>>>(predT, Wd, bd, out + 0, out + 518400);
    decode_kernel<<<720, 256, 0, stream>>>(teacher, Wd, bd, out + 172800, out + 519120);
    target_kernel<<<720, 256, 0, stream>>>(x, out + 345600, out + 519840);
}